// Round 13
// baseline (8658.044 us; speedup 1.0000x reference)
//
#include <hip/hip_runtime.h>
#include <hip/hip_bf16.h>
#include <math.h>
#include <type_traits>

#define HIDDEN 256
#define SEQ 2048
#define BATCH 64
#define INSZ 128
#define OUTSZ 64
#define DTC 0.05f

typedef _Float16 f16x8 __attribute__((ext_vector_type(8)));
typedef float f32x4 __attribute__((ext_vector_type(4)));

// ---------------- K0: complexity net + alphas ----------------
__global__ __launch_bounds__(1024) void prep_kernel(
    const float* __restrict__ x, const float* __restrict__ cw1, const float* __restrict__ cb1,
    const float* __restrict__ cw2, const float* __restrict__ cb2,
    const float* __restrict__ tau_b, const float* __restrict__ tmw, const float* __restrict__ tmb,
    float* __restrict__ alphas)   // [3][64]
{
    __shared__ float p_lds[8][128];
    __shared__ float xm[128];
    __shared__ float t1[64];
    int b = blockIdx.x;
    int tid = threadIdx.x;
    int c = tid & 127, sh = tid >> 7;
    const float* xb = x + (size_t)b * SEQ * INSZ;
    float s = 0.f;
    for (int t = sh * 256; t < (sh + 1) * 256; ++t) s += xb[(size_t)t * INSZ + c];
    p_lds[sh][c] = s;
    __syncthreads();
    if (tid < 128) {
        float m = 0.f;
        #pragma unroll
        for (int i = 0; i < 8; ++i) m += p_lds[i][tid];
        xm[tid] = m / (float)SEQ;
    }
    __syncthreads();
    if (tid < 64) {
        float acc = cb1[tid];
        for (int k = 0; k < 128; ++k) acc += xm[k] * cw1[tid * 128 + k];
        t1[tid] = fmaxf(acc, 0.f);
    }
    __syncthreads();
    if (tid == 0) {
        float acc = cb2[0];
        for (int k = 0; k < 64; ++k) acc += t1[k] * cw2[k];
        float comp = 1.f / (1.f + expf(-acc));
        for (int i = 0; i < 3; ++i) {
            float lg[4], mx = -1e30f;
            for (int j = 0; j < 4; ++j) { lg[j] = comp * tmw[i * 4 + j] + tmb[i * 4 + j]; mx = fmaxf(mx, lg[j]); }
            float den = 0.f;
            for (int j = 0; j < 4; ++j) { lg[j] = expf(lg[j] - mx); den += lg[j]; }
            float mt = 0.f;
            for (int j = 0; j < 4; ++j) mt += tau_b[i * 4 + j] * (lg[j] / den);
            alphas[i * 64 + b] = expf(-DTC / mt);
        }
    }
}

// ---------------- Wf = W_in0 @ pw  (256x128), bf = W_in0 @ pb + bias0 ----------------
__global__ __launch_bounds__(128) void wf_kernel(
    const float* __restrict__ W_in0, const float* __restrict__ pw,
    const float* __restrict__ pb, const float* __restrict__ bias0,
    float* __restrict__ Wf, float* __restrict__ bf)
{
    __shared__ float wrow[256];
    int j = blockIdx.x, k = threadIdx.x;
    for (int m = k; m < 256; m += 128) wrow[m] = W_in0[j * 256 + m];
    __syncthreads();
    float s = 0.f;
    for (int m = 0; m < 256; ++m) s = fmaf(wrow[m], pw[m * 128 + k], s);
    Wf[j * 128 + k] = s;
    if (k == 0) {
        float sb = bias0[j];
        for (int m = 0; m < 256; ++m) sb = fmaf(wrow[m], pb[m], sb);
        bf[j] = sb;
    }
}

// ---------------- streaming register-weight GEMM (unchanged, fp32) ----------------
template<int KQ, int NR>
__global__ __launch_bounds__(512) void gemm_stream(
    const float* A, const float* __restrict__ W, const float* __restrict__ bias,
    float* C, int rows_per_wg)
{
    constexpr int K = KQ * 64;
    constexpr int JB = 8 / KQ;
    __shared__ float a_lds[4 * K];
    __shared__ float p_lds[KQ][4][256];
    __shared__ float bias_l[256];
    int tid = threadIdx.x;
    int w = tid >> 6, l = tid & 63;
    int q = w % KQ, jb = w / KQ;

    float4 wr[NR][16];
    #pragma unroll
    for (int r = 0; r < NR; ++r) {
        int j = jb * 64 + l + r * (JB * 64);
        const float4* wp = (const float4*)(W + (size_t)j * K + q * 64);
        #pragma unroll
        for (int m = 0; m < 16; ++m) wr[r][m] = wp[m];
    }
    if (tid < 256) bias_l[tid] = bias[tid];

    size_t row0 = (size_t)blockIdx.x * rows_per_wg;
    for (int it = 0; it < rows_per_wg; it += 4) {
        size_t m0 = row0 + it;
        __syncthreads();
        #pragma unroll
        for (int e = 0; e < K / 128; ++e)
            a_lds[tid + e * 512] = A[m0 * K + tid + e * 512];
        __syncthreads();

        float acc[4][NR];
        #pragma unroll
        for (int r4 = 0; r4 < 4; ++r4)
            #pragma unroll
            for (int r = 0; r < NR; ++r) acc[r4][r] = 0.f;

        #pragma unroll
        for (int r4 = 0; r4 < 4; ++r4) {
            const float4* hp = (const float4*)(a_lds + r4 * K + q * 64);
            #pragma unroll
            for (int m = 0; m < 16; ++m) {
                float4 hv = hp[m];
                #pragma unroll
                for (int r = 0; r < NR; ++r) {
                    acc[r4][r] = fmaf(wr[r][m].x, hv.x, acc[r4][r]);
                    acc[r4][r] = fmaf(wr[r][m].y, hv.y, acc[r4][r]);
                    acc[r4][r] = fmaf(wr[r][m].z, hv.z, acc[r4][r]);
                    acc[r4][r] = fmaf(wr[r][m].w, hv.w, acc[r4][r]);
                }
            }
        }
        #pragma unroll
        for (int r4 = 0; r4 < 4; ++r4)
            #pragma unroll
            for (int r = 0; r < NR; ++r)
                p_lds[q][r4][jb * 64 + l + r * (JB * 64)] = acc[r4][r];
        __syncthreads();
        if (tid < 256) {
            #pragma unroll
            for (int r4 = 0; r4 < 4; ++r4) {
                float s2 = bias_l[tid];
                #pragma unroll
                for (int qq = 0; qq < KQ; ++qq) s2 += p_lds[qq][r4][tid];
                C[(m0 + r4) * 256 + tid] = s2;
            }
        }
    }
}

__device__ __forceinline__ float fast_tanh(float x) {
    float ex = __expf(2.f * x);                 // v_exp based
    float r = __builtin_amdgcn_rcpf(ex + 1.f);  // v_rcp_f32
    return 1.f - 2.f * r;                       // ex=inf -> 1, ex=0 -> -1
}

__device__ __forceinline__ unsigned pkrtz(float a, float b) {
    return __builtin_bit_cast(unsigned, __builtin_amdgcn_cvt_pkrtz(a, b));
}

// LDS-only barrier: waits ds ops (lgkmcnt) but leaves global loads/stores in flight.
__device__ __forceinline__ void barrier_lds_only() {
    asm volatile("s_waitcnt lgkmcnt(0)\n\ts_barrier" ::: "memory");
}

// ---------------- MFMA scan: 64 WGs x 1 batch, matvec on the matrix pipe ----------------
// Wave w owns output rows [w*64, w*64+64) as 4 m-tiles of 16. h lives in LDS as ONE
// 256-f16 row (512 B), double-buffered. mfma_f32_16x16x32_f16 with only B-col 0 useful:
//   A: m=lane&15, k=8*(lane>>4)+e  (W_rec fragments, register-resident, 128 VGPR)
//   B: n=lane&15, k=8*(lane>>4)+e  -> value h[k], independent of n => 16-lane broadcast read
//   D: n=lane&15, m=(lane>>4)*4+r  -> col 0 lives in lanes bl==0 (4/wave), which run the
//      tanh/EMA epilogue on 16 outputs each and rewrite the h row (uint2 per m-tile,
//      banks cover all 32 exactly once). MFMA inst count is n-independent: the idle
//      15 columns cost nothing extra. ext staged global->reg->LDS ping-pong (coalesced
//      1 KB loads by all 256 threads, 2-step pipeline) to keep VGPR ~210.
__global__ __launch_bounds__(256, 1) void scan_kernel(
    float* buf,                       // [B][S][256]: in = ext, out = h_seq (in place)
    const float* __restrict__ W_rec,  // [256][256]
    const float* __restrict__ alphas, // [64]
    float* __restrict__ h_carry,      // [64][256]
    int layer, int write_all)
{
    __shared__ alignas(16) _Float16 hlds[2][256];   // 2 x 512 B
    __shared__ alignas(16) float    elds[2][256];   // 2 x 1 KB
    const int tid = threadIdx.x;
    const int wave = tid >> 6, lane = tid & 63;
    const int bl = lane & 15, q = lane >> 4;
    const int b = blockIdx.x;
    const bool act = (bl == 0);

    // ---- A fragments: W rows [wave*64, wave*64+64), 4 m-tiles x 8 k-tiles ----
    f16x8 afrag[4][8];
    #pragma unroll
    for (int mt = 0; mt < 4; ++mt) {
        const float* wr = W_rec + (size_t)(wave * 64 + mt * 16 + bl) * 256;
        #pragma unroll
        for (int kt = 0; kt < 8; ++kt) {
            const float4* wp = (const float4*)(wr + kt * 32 + q * 8);
            float4 wa = wp[0], wb4 = wp[1];
            uint4 u = { pkrtz(wa.x, wa.y), pkrtz(wa.z, wa.w),
                        pkrtz(wb4.x, wb4.y), pkrtz(wb4.z, wb4.w) };
            afrag[mt][kt] = __builtin_bit_cast(f16x8, u);
        }
    }

    const float alpha = alphas[b], onema = 1.f - alpha;
    float* bb = buf + (size_t)b * SEQ * HIDDEN;

    // ---- h registers on active lanes: hreg[mt][r] = h[wave*64 + mt*16 + q*4 + r] ----
    f32x4 hreg[4];
    #pragma unroll
    for (int mt = 0; mt < 4; ++mt) hreg[mt] = (f32x4){0.f, 0.f, 0.f, 0.f};
    if (act && layer != 0) {
        #pragma unroll
        for (int mt = 0; mt < 4; ++mt)
            hreg[mt] = *(const f32x4*)(h_carry + b * 256 + wave * 64 + mt * 16 + q * 4);
    }
    if (act) {
        #pragma unroll
        for (int mt = 0; mt < 4; ++mt) {
            uint2 p = { pkrtz(hreg[mt][0], hreg[mt][1]), pkrtz(hreg[mt][2], hreg[mt][3]) };
            *(uint2*)((char*)&hlds[0][0] + wave * 128 + mt * 32 + q * 8) = p;
        }
    }
    elds[0][tid] = bb[tid];                    // ext[0] staged
    float g_prev = bb[256 + tid];              // ext[1] in reg
    __syncthreads();

    auto step = [&](auto CB, int t) {
        constexpr int CUR = decltype(CB)::value;
        const char* rb = (const char*)&hlds[CUR][0];
        char* wb = (char*)&hlds[CUR ^ 1][0];
        // B fragments: 8 broadcast ds_read_b128 (4 distinct addrs/wave, free)
        uint4 bq0 = *(const uint4*)(rb + q * 16);
        uint4 bq1 = *(const uint4*)(rb + 64 + q * 16);
        uint4 bq2 = *(const uint4*)(rb + 128 + q * 16);
        uint4 bq3 = *(const uint4*)(rb + 192 + q * 16);
        uint4 bq4 = *(const uint4*)(rb + 256 + q * 16);
        uint4 bq5 = *(const uint4*)(rb + 320 + q * 16);
        uint4 bq6 = *(const uint4*)(rb + 384 + q * 16);
        uint4 bq7 = *(const uint4*)(rb + 448 + q * 16);
        // ext[t] for this step's epilogue (written to elds[CUR] before last barrier)
        f32x4 ec0, ec1, ec2, ec3;
        if (act) {
            const float* eb = &elds[CUR][wave * 64 + q * 4];
            ec0 = *(const f32x4*)(eb);
            ec1 = *(const f32x4*)(eb + 16);
            ec2 = *(const f32x4*)(eb + 32);
            ec3 = *(const f32x4*)(eb + 48);
        }
        // coalesced 2-ahead global prefetch by all 256 threads
        float g_new = 0.f;
        if (t + 2 < SEQ) g_new = bb[(size_t)(t + 2) * HIDDEN + tid];

        f32x4 a0 = {0.f,0.f,0.f,0.f}, a1 = {0.f,0.f,0.f,0.f};
        f32x4 a2 = {0.f,0.f,0.f,0.f}, a3 = {0.f,0.f,0.f,0.f};
        #define MSTEP(BQ, KT) { f16x8 bf = __builtin_bit_cast(f16x8, BQ);                  \
            a0 = __builtin_amdgcn_mfma_f32_16x16x32_f16(afrag[0][KT], bf, a0, 0, 0, 0);    \
            a1 = __builtin_amdgcn_mfma_f32_16x16x32_f16(afrag[1][KT], bf, a1, 0, 0, 0);    \
            a2 = __builtin_amdgcn_mfma_f32_16x16x32_f16(afrag[2][KT], bf, a2, 0, 0, 0);    \
            a3 = __builtin_amdgcn_mfma_f32_16x16x32_f16(afrag[3][KT], bf, a3, 0, 0, 0); }
        MSTEP(bq0, 0) MSTEP(bq1, 1) MSTEP(bq2, 2) MSTEP(bq3, 3)
        MSTEP(bq4, 4) MSTEP(bq5, 5) MSTEP(bq6, 6) MSTEP(bq7, 7)
        #undef MSTEP

        if (act) {
            #define EPI(AV, ECV, MT) {                                                     \
                f32x4 h = hreg[MT];                                                        \
                h[0] = alpha * h[0] + onema * fast_tanh(AV[0] + ECV[0]);                   \
                h[1] = alpha * h[1] + onema * fast_tanh(AV[1] + ECV[1]);                   \
                h[2] = alpha * h[2] + onema * fast_tanh(AV[2] + ECV[2]);                   \
                h[3] = alpha * h[3] + onema * fast_tanh(AV[3] + ECV[3]);                   \
                hreg[MT] = h;                                                              \
                uint2 p = { pkrtz(h[0], h[1]), pkrtz(h[2], h[3]) };                        \
                *(uint2*)(wb + wave * 128 + MT * 32 + q * 8) = p;                          \
                if (write_all) *(f32x4*)(bb + (size_t)t * HIDDEN + wave * 64 + MT * 16 + q * 4) = h; }
            EPI(a0, ec0, 0) EPI(a1, ec1, 1) EPI(a2, ec2, 2) EPI(a3, ec3, 3)
            #undef EPI
        }
        elds[CUR ^ 1][tid] = g_prev;           // stage ext[t+1] for next step
        barrier_lds_only();                    // lgkmcnt(0)+s_barrier; vm ops in flight
        g_prev = g_new;
    };

    for (int t = 0; t < SEQ; t += 2) {
        step(std::integral_constant<int, 0>{}, t);
        step(std::integral_constant<int, 1>{}, t + 1);
    }

    if (act) {
        #pragma unroll
        for (int mt = 0; mt < 4; ++mt)
            *(f32x4*)(h_carry + b * 256 + wave * 64 + mt * 16 + q * 4) = hreg[mt];
    }
}

// ---------------- final projection from h_carry ----------------
__global__ __launch_bounds__(256) void outproj_kernel(
    const float* __restrict__ h_carry, const float* __restrict__ ow, const float* __restrict__ ob,
    float* __restrict__ out)
{
    __shared__ float h_l[256];
    __shared__ float p_lds[4][64];
    int b = blockIdx.x;
    int tid = threadIdx.x;
    h_l[tid] = h_carry[b * 256 + tid];
    __syncthreads();
    int o = tid & 63, qq = tid >> 6;
    float s = 0.f;
    const float4* wp = (const float4*)(ow + o * 256 + qq * 64);
    const float4* hp = (const float4*)(h_l + qq * 64);
    #pragma unroll
    for (int m = 0; m < 16; ++m) {
        float4 wv = wp[m]; float4 hv = hp[m];
        s = fmaf(wv.x, hv.x, s); s = fmaf(wv.y, hv.y, s);
        s = fmaf(wv.z, hv.z, s); s = fmaf(wv.w, hv.w, s);
    }
    p_lds[qq][o] = s;
    __syncthreads();
    if (tid < 64)
        out[b * 64 + tid] = p_lds[0][tid] + p_lds[1][tid] + p_lds[2][tid] + p_lds[3][tid] + ob[tid];
}

extern "C" void kernel_launch(void* const* d_in, const int* in_sizes, int n_in,
                              void* d_out, int out_size, void* d_ws, size_t ws_size,
                              hipStream_t stream)
{
    const float* x     = (const float*)d_in[0];
    const float* cw1   = (const float*)d_in[1];
    const float* cb1   = (const float*)d_in[2];
    const float* cw2   = (const float*)d_in[3];
    const float* cb2   = (const float*)d_in[4];
    const float* pw    = (const float*)d_in[5];
    const float* pb    = (const float*)d_in[6];
    const float* W_rec = (const float*)d_in[7];
    const float* W_in  = (const float*)d_in[8];
    const float* bias  = (const float*)d_in[9];
    const float* tau_b = (const float*)d_in[10];
    const float* tmw   = (const float*)d_in[11];
    const float* tmb   = (const float*)d_in[12];
    const float* ow    = (const float*)d_in[13];
    const float* ob    = (const float*)d_in[14];
    float* out = (float*)d_out;

    char* ws = (char*)d_ws;
    float* alphas  = (float*)ws;                       // 192 f
    float* h_carry = (float*)(ws + 4096);              // 64*256 f
    float* bf      = (float*)(ws + 69632);             // 256 f
    float* Wf      = (float*)(ws + 70656);             // 256*128 f
    float* buf     = (float*)(ws + 1048576);           // [64][2048][256] f32 = 134.2MB

    const int M = BATCH * SEQ;          // 131072 rows
    const int ROWS_PER_WG = M / 256;    // 512

    prep_kernel<<<64, 1024, 0, stream>>>(x, cw1, cb1, cw2, cb2, tau_b, tmw, tmb, alphas);
    wf_kernel<<<256, 128, 0, stream>>>(W_in, pw, pb, bias, Wf, bf);

    // layer 0 ext = x @ Wf.T + bf  (input projection fused away)
    gemm_stream<2, 1><<<256, 512, 0, stream>>>(x, Wf, bf, buf, ROWS_PER_WG);
    scan_kernel<<<64, 256, 0, stream>>>(buf, W_rec, alphas, h_carry, 0, 1);

    gemm_stream<4, 2><<<256, 512, 0, stream>>>(buf, W_in + (size_t)1 * HIDDEN * HIDDEN,
                                               bias + 1 * HIDDEN, buf, ROWS_PER_WG);
    scan_kernel<<<64, 256, 0, stream>>>(buf, W_rec + (size_t)1 * HIDDEN * HIDDEN,
                                        alphas + 64, h_carry, 1, 1);

    gemm_stream<4, 2><<<256, 512, 0, stream>>>(buf, W_in + (size_t)2 * HIDDEN * HIDDEN,
                                               bias + 2 * HIDDEN, buf, ROWS_PER_WG);
    scan_kernel<<<64, 256, 0, stream>>>(buf, W_rec + (size_t)2 * HIDDEN * HIDDEN,
                                        alphas + 128, h_carry, 2, 0);

    outproj_kernel<<<64, 256, 0, stream>>>(h_carry, ow, ob, out);
}

// Round 14
// 3307.771 us; speedup vs baseline: 2.6175x; 2.6175x over previous
//
#include <hip/hip_runtime.h>
#include <hip/hip_bf16.h>
#include <math.h>
#include <type_traits>

#define HIDDEN 256
#define SEQ 2048
#define BATCH 64
#define INSZ 128
#define OUTSZ 64
#define DTC 0.05f

typedef _Float16 h2 __attribute__((ext_vector_type(2)));
typedef _Float16 f16x8 __attribute__((ext_vector_type(8)));
typedef float f32x4 __attribute__((ext_vector_type(4)));

// ---------------- K0: complexity net + alphas ----------------
__global__ __launch_bounds__(1024) void prep_kernel(
    const float* __restrict__ x, const float* __restrict__ cw1, const float* __restrict__ cb1,
    const float* __restrict__ cw2, const float* __restrict__ cb2,
    const float* __restrict__ tau_b, const float* __restrict__ tmw, const float* __restrict__ tmb,
    float* __restrict__ alphas)   // [3][64]
{
    __shared__ float p_lds[8][128];
    __shared__ float xm[128];
    __shared__ float t1[64];
    int b = blockIdx.x;
    int tid = threadIdx.x;
    int c = tid & 127, sh = tid >> 7;
    const float* xb = x + (size_t)b * SEQ * INSZ;
    float s = 0.f;
    for (int t = sh * 256; t < (sh + 1) * 256; ++t) s += xb[(size_t)t * INSZ + c];
    p_lds[sh][c] = s;
    __syncthreads();
    if (tid < 128) {
        float m = 0.f;
        #pragma unroll
        for (int i = 0; i < 8; ++i) m += p_lds[i][tid];
        xm[tid] = m / (float)SEQ;
    }
    __syncthreads();
    if (tid < 64) {
        float acc = cb1[tid];
        for (int k = 0; k < 128; ++k) acc += xm[k] * cw1[tid * 128 + k];
        t1[tid] = fmaxf(acc, 0.f);
    }
    __syncthreads();
    if (tid == 0) {
        float acc = cb2[0];
        for (int k = 0; k < 64; ++k) acc += t1[k] * cw2[k];
        float comp = 1.f / (1.f + expf(-acc));
        for (int i = 0; i < 3; ++i) {
            float lg[4], mx = -1e30f;
            for (int j = 0; j < 4; ++j) { lg[j] = comp * tmw[i * 4 + j] + tmb[i * 4 + j]; mx = fmaxf(mx, lg[j]); }
            float den = 0.f;
            for (int j = 0; j < 4; ++j) { lg[j] = expf(lg[j] - mx); den += lg[j]; }
            float mt = 0.f;
            for (int j = 0; j < 4; ++j) mt += tau_b[i * 4 + j] * (lg[j] / den);
            alphas[i * 64 + b] = expf(-DTC / mt);
        }
    }
}

// ---------------- Wf = W_in0 @ pw  (256x128), bf = W_in0 @ pb + bias0 ----------------
__global__ __launch_bounds__(128) void wf_kernel(
    const float* __restrict__ W_in0, const float* __restrict__ pw,
    const float* __restrict__ pb, const float* __restrict__ bias0,
    float* __restrict__ Wf, float* __restrict__ bf)
{
    __shared__ float wrow[256];
    int j = blockIdx.x, k = threadIdx.x;
    for (int m = k; m < 256; m += 128) wrow[m] = W_in0[j * 256 + m];
    __syncthreads();
    float s = 0.f;
    for (int m = 0; m < 256; ++m) s = fmaf(wrow[m], pw[m * 128 + k], s);
    Wf[j * 128 + k] = s;
    if (k == 0) {
        float sb = bias0[j];
        for (int m = 0; m < 256; ++m) sb = fmaf(wrow[m], pb[m], sb);
        bf[j] = sb;
    }
}

__device__ __forceinline__ unsigned pkrtz(float a, float b) {
    return __builtin_bit_cast(unsigned, __builtin_amdgcn_cvt_pkrtz(a, b));
}

// ---------------- MFMA GEMM: C[M][256] = A[M][KD] @ W[256][KD]^T + bias ----------------
// Tile 32 rows x 256 cols per WG; 4 waves, wave w covers cols [w*64, w*64+64) (4 n-tiles).
// B (=W) fragments register-resident; A staged to LDS (f16, XOR-swizzled, T2 recipe).
// Fragment mapping (verified r12/r13): arg0 A: m=lane&15,k=8*(lane>>4)+e;
// arg1 B: n=lane&15,k likewise; D: col=lane&15, row=(lane>>4)*4+r.
// In-place safe vs f16 A packed in C's rows: all A reads complete before C writes (same WG),
// different WGs touch disjoint rows.
template<int KD, bool SRCF32>
__global__ __launch_bounds__(256, 2) void mfma_gemm(
    const float* __restrict__ Asrc,  // SRCF32: f32 [M][KD]; else f16 packed in 1KB-stride rows
    const float* __restrict__ W,     // [256][KD] f32
    const float* __restrict__ bias,  // [256]
    float* __restrict__ C)           // [M][256] f32
{
    constexpr int KT = KD / 32;
    constexpr int ROWB = KD * 2;     // LDS row bytes (f16)
    __shared__ alignas(16) char alds[32 * ROWB];
    const int tid = threadIdx.x;
    const int wave = tid >> 6, lane = tid & 63;
    const int bl = lane & 15, q = lane >> 4;
    const int m0 = blockIdx.x * 32;

    // B fragments: W rows (= C cols) [wave*64, wave*64+64)
    f16x8 bfrag[4][KT];
    float bv[4];
    #pragma unroll
    for (int nt = 0; nt < 4; ++nt) {
        int n = wave * 64 + nt * 16 + bl;
        const float* wr = W + (size_t)n * KD;
        #pragma unroll
        for (int kt = 0; kt < KT; ++kt) {
            const float4* wp = (const float4*)(wr + kt * 32 + q * 8);
            float4 u0 = wp[0], u1 = wp[1];
            uint4 u = { pkrtz(u0.x, u0.y), pkrtz(u0.z, u0.w),
                        pkrtz(u1.x, u1.y), pkrtz(u1.z, u1.w) };
            bfrag[nt][kt] = __builtin_bit_cast(f16x8, u);
        }
        bv[nt] = bias[n];
    }

    // Stage A rows [m0, m0+32) as f16 into LDS, 16B-chunk XOR swizzle by row&7
    if (SRCF32) {
        #pragma unroll
        for (int it = 0; it < KD / 64; ++it) {
            int idx = tid + it * 256;
            int row = idx >> 4, chunk = idx & 15;
            const float4* sp = (const float4*)(Asrc + (size_t)(m0 + row) * KD + chunk * 8);
            float4 f0 = sp[0], f1 = sp[1];
            uint4 u = { pkrtz(f0.x, f0.y), pkrtz(f0.z, f0.w),
                        pkrtz(f1.x, f1.y), pkrtz(f1.z, f1.w) };
            *(uint4*)(alds + row * ROWB + ((chunk * 16) ^ ((row & 7) << 4))) = u;
        }
    } else {
        #pragma unroll
        for (int it = 0; it < KD / 32; ++it) {
            int idx = tid + it * 256;
            int row = idx >> 5, chunk = idx & 31;
            uint4 u = *(const uint4*)((const char*)Asrc + (size_t)(m0 + row) * 1024 + chunk * 16);
            *(uint4*)(alds + row * ROWB + ((chunk * 16) ^ ((row & 7) << 4))) = u;
        }
    }
    __syncthreads();

    f32x4 acc[2][4];
    #pragma unroll
    for (int mt = 0; mt < 2; ++mt)
        #pragma unroll
        for (int nt = 0; nt < 4; ++nt) acc[mt][nt] = (f32x4){0.f, 0.f, 0.f, 0.f};

    #pragma unroll
    for (int kt = 0; kt < KT; ++kt) {
        int inner = kt * 64 + q * 16;
        f16x8 a0 = __builtin_bit_cast(f16x8,
            *(const uint4*)(alds + (0 * 16 + bl) * ROWB + (inner ^ ((bl & 7) << 4))));
        f16x8 a1 = __builtin_bit_cast(f16x8,
            *(const uint4*)(alds + (1 * 16 + bl) * ROWB + (inner ^ ((bl & 7) << 4))));
        #pragma unroll
        for (int nt = 0; nt < 4; ++nt) {
            acc[0][nt] = __builtin_amdgcn_mfma_f32_16x16x32_f16(a0, bfrag[nt][kt], acc[0][nt], 0, 0, 0);
            acc[1][nt] = __builtin_amdgcn_mfma_f32_16x16x32_f16(a1, bfrag[nt][kt], acc[1][nt], 0, 0, 0);
        }
    }

    #pragma unroll
    for (int mt = 0; mt < 2; ++mt)
        #pragma unroll
        for (int nt = 0; nt < 4; ++nt) {
            int col = wave * 64 + nt * 16 + bl;
            #pragma unroll
            for (int r = 0; r < 4; ++r) {
                int row = m0 + mt * 16 + q * 4 + r;
                C[(size_t)row * 256 + col] = acc[mt][nt][r] + bv[nt];
            }
        }
}

__device__ __forceinline__ float fast_tanh(float x) {
    float ex = __expf(2.f * x);                 // v_exp based
    float r = __builtin_amdgcn_rcpf(ex + 1.f);  // v_rcp_f32
    return 1.f - 2.f * r;                       // ex=inf -> 1, ex=0 -> -1
}

// cross-lane adds on VALU (DPP quad_perm) — no LDS pipe
__device__ __forceinline__ float dpp_add_xor1(float v) {
    int x = __builtin_amdgcn_update_dpp(0, __builtin_bit_cast(int, v), 0xB1, 0xF, 0xF, false);
    return v + __builtin_bit_cast(float, x);
}
__device__ __forceinline__ float dpp_add_xor2(float v) {
    int x = __builtin_amdgcn_update_dpp(0, __builtin_bit_cast(int, v), 0x4E, 0xF, 0xF, false);
    return v + __builtin_bit_cast(float, x);
}

// LDS-only barrier: waits ds ops (lgkmcnt) but leaves global loads/stores in flight.
__device__ __forceinline__ void barrier_lds_only() {
    asm volatile("s_waitcnt lgkmcnt(0)\n\ts_barrier" ::: "memory");
}

#if __has_builtin(__builtin_amdgcn_fdot2)
#define FDOT2(a, b, c) __builtin_amdgcn_fdot2((a), (b), (c), false)
#else
#define FDOT2(a, b, c) fmaf((float)(a).x, (float)(b).x, fmaf((float)(a).y, (float)(b).y, (c)))
#endif

// ---------------- scan (r8 structure): 256 threads, thread tid owns output o=tid ----------------
// h_seq now stored f16 into the first 512B of each consumed ext row (feeds mfma_gemm).
__global__ __launch_bounds__(256, 1) void scan_kernel(
    float* buf,                       // [B][S][256]: in = ext f32, out = h f16 (packed in rows)
    const float* __restrict__ W_rec,  // [256][256]
    const float* __restrict__ alphas, // [64]
    float* __restrict__ h_carry,      // [64][256]
    int layer, int write_all)
{
    __shared__ alignas(16) unsigned short h16[2][4 * 72];  // 2 x 576B
    int b = blockIdx.x;
    int tid = threadIdx.x;
    int g = tid >> 2;       // 0..63
    int kq = tid & 3;       // 0..3
    int j = kq;             // output within group this lane finalizes
    int o = tid;            // == g*4 + j

    // weights rows 4g..4g+3, cols [64kq, 64kq+64), as 32 half2 per row = 128 VGPR
    h2 wh[4][32];
    #pragma unroll
    for (int jj = 0; jj < 4; ++jj) {
        const float4* wp = (const float4*)(W_rec + (size_t)(g * 4 + jj) * 256 + kq * 64);
        #pragma unroll
        for (int m = 0; m < 16; ++m) {
            float4 wv = wp[m];
            wh[jj][2 * m]     = __builtin_bit_cast(h2, __builtin_amdgcn_cvt_pkrtz(wv.x, wv.y));
            wh[jj][2 * m + 1] = __builtin_bit_cast(h2, __builtin_amdgcn_cvt_pkrtz(wv.z, wv.w));
        }
    }

    float alpha = alphas[b];
    float onema = 1.f - alpha;
    float* bb = buf + (size_t)b * SEQ * HIDDEN;

    float h_reg = (layer == 0) ? 0.f : h_carry[b * 256 + o];
    // per-thread LDS addresses (loop-invariant)
    const uint4* hp0 = (const uint4*)((char*)&h16[0][0] + kq * 144);
    const uint4* hp1 = (const uint4*)((char*)&h16[1][0] + kq * 144);
    _Float16* wr0 = (_Float16*)((char*)&h16[0][0] + (o >> 6) * 144 + (o & 63) * 2);
    _Float16* wr1 = (_Float16*)((char*)&h16[1][0] + (o >> 6) * 144 + (o & 63) * 2);

    *wr0 = (_Float16)h_reg;                    // initial h into buffer 0
    float e_cur = bb[o];                       // ext[0]
    float e_n1  = bb[(size_t)1 * HIDDEN + o];  // ext[1]
    __syncthreads();

    auto step = [&](auto CB, int t) {
        constexpr int CUR = decltype(CB)::value;
        const uint4* hp = (CUR == 0) ? hp0 : hp1;
        // issue ALL 8 ds_read_b128 back-to-back (one LDS latency)
        uint4 q0 = hp[0], q1 = hp[1], q2 = hp[2], q3 = hp[3];
        uint4 q4 = hp[4], q5 = hp[5], q6 = hp[6], q7 = hp[7];
        float e_n2 = 0.f;
        if (t + 2 < SEQ) e_n2 = bb[(size_t)(t + 2) * HIDDEN + o];  // 2-ahead prefetch

        float a0 = 0.f, a1 = 0.f, a2 = 0.f, a3 = 0.f;
        #define DOTQ(QV, M)                                                              \
        {   h2 hv0 = __builtin_bit_cast(h2, (QV).x), hv1 = __builtin_bit_cast(h2, (QV).y), \
               hv2 = __builtin_bit_cast(h2, (QV).z), hv3 = __builtin_bit_cast(h2, (QV).w); \
            a0 = FDOT2(wh[0][4*(M)], hv0, a0); a0 = FDOT2(wh[0][4*(M)+1], hv1, a0);        \
            a0 = FDOT2(wh[0][4*(M)+2], hv2, a0); a0 = FDOT2(wh[0][4*(M)+3], hv3, a0);      \
            a1 = FDOT2(wh[1][4*(M)], hv0, a1); a1 = FDOT2(wh[1][4*(M)+1], hv1, a1);        \
            a1 = FDOT2(wh[1][4*(M)+2], hv2, a1); a1 = FDOT2(wh[1][4*(M)+3], hv3, a1);      \
            a2 = FDOT2(wh[2][4*(M)], hv0, a2); a2 = FDOT2(wh[2][4*(M)+1], hv1, a2);        \
            a2 = FDOT2(wh[2][4*(M)+2], hv2, a2); a2 = FDOT2(wh[2][4*(M)+3], hv3, a2);      \
            a3 = FDOT2(wh[3][4*(M)], hv0, a3); a3 = FDOT2(wh[3][4*(M)+1], hv1, a3);        \
            a3 = FDOT2(wh[3][4*(M)+2], hv2, a3); a3 = FDOT2(wh[3][4*(M)+3], hv3, a3); }
        DOTQ(q0, 0) DOTQ(q1, 1) DOTQ(q2, 2) DOTQ(q3, 3)
        DOTQ(q4, 4) DOTQ(q5, 5) DOTQ(q6, 6) DOTQ(q7, 7)
        #undef DOTQ

        // reduce over the 4 k-segments: 2 DPP levels, no LDS
        a0 = dpp_add_xor1(a0); a1 = dpp_add_xor1(a1); a2 = dpp_add_xor1(a2); a3 = dpp_add_xor1(a3);
        a0 = dpp_add_xor2(a0); a1 = dpp_add_xor2(a1); a2 = dpp_add_xor2(a2); a3 = dpp_add_xor2(a3);
        float acc = (j == 0) ? a0 : (j == 1) ? a1 : (j == 2) ? a2 : a3;

        float act = fast_tanh(acc + e_cur);
        h_reg = alpha * h_reg + onema * act;
        *((CUR == 0) ? wr1 : wr0) = (_Float16)h_reg;         // h for next step
        if (write_all)                                        // h f16 over consumed ext row
            *((_Float16*)(bb + (size_t)t * HIDDEN) + o) = (_Float16)h_reg;
        barrier_lds_only();   // lgkmcnt(0)+s_barrier; global ops stay in flight
        e_cur = e_n1;
        e_n1 = e_n2;
    };

    for (int t = 0; t < SEQ; t += 2) {
        step(std::integral_constant<int, 0>{}, t);
        step(std::integral_constant<int, 1>{}, t + 1);
    }
    h_carry[b * 256 + o] = h_reg;
}

// ---------------- final projection from h_carry ----------------
__global__ __launch_bounds__(256) void outproj_kernel(
    const float* __restrict__ h_carry, const float* __restrict__ ow, const float* __restrict__ ob,
    float* __restrict__ out)
{
    __shared__ float h_l[256];
    __shared__ float p_lds[4][64];
    int b = blockIdx.x;
    int tid = threadIdx.x;
    h_l[tid] = h_carry[b * 256 + tid];
    __syncthreads();
    int o = tid & 63, qq = tid >> 6;
    float s = 0.f;
    const float4* wp = (const float4*)(ow + o * 256 + qq * 64);
    const float4* hp = (const float4*)(h_l + qq * 64);
    #pragma unroll
    for (int m = 0; m < 16; ++m) {
        float4 wv = wp[m]; float4 hv = hp[m];
        s = fmaf(wv.x, hv.x, s); s = fmaf(wv.y, hv.y, s);
        s = fmaf(wv.z, hv.z, s); s = fmaf(wv.w, hv.w, s);
    }
    p_lds[qq][o] = s;
    __syncthreads();
    if (tid < 64)
        out[b * 64 + tid] = p_lds[0][tid] + p_lds[1][tid] + p_lds[2][tid] + p_lds[3][tid] + ob[tid];
}

extern "C" void kernel_launch(void* const* d_in, const int* in_sizes, int n_in,
                              void* d_out, int out_size, void* d_ws, size_t ws_size,
                              hipStream_t stream)
{
    const float* x     = (const float*)d_in[0];
    const float* cw1   = (const float*)d_in[1];
    const float* cb1   = (const float*)d_in[2];
    const float* cw2   = (const float*)d_in[3];
    const float* cb2   = (const float*)d_in[4];
    const float* pw    = (const float*)d_in[5];
    const float* pb    = (const float*)d_in[6];
    const float* W_rec = (const float*)d_in[7];
    const float* W_in  = (const float*)d_in[8];
    const float* bias  = (const float*)d_in[9];
    const float* tau_b = (const float*)d_in[10];
    const float* tmw   = (const float*)d_in[11];
    const float* tmb   = (const float*)d_in[12];
    const float* ow    = (const float*)d_in[13];
    const float* ob    = (const float*)d_in[14];
    float* out = (float*)d_out;

    char* ws = (char*)d_ws;
    float* alphas  = (float*)ws;                       // 192 f
    float* h_carry = (float*)(ws + 4096);              // 64*256 f
    float* bf      = (float*)(ws + 69632);             // 256 f
    float* Wf      = (float*)(ws + 70656);             // 256*128 f
    float* buf     = (float*)(ws + 1048576);           // [64][2048][256] f32 = 134.2MB

    const int MROWS = BATCH * SEQ;      // 131072

    prep_kernel<<<64, 1024, 0, stream>>>(x, cw1, cb1, cw2, cb2, tau_b, tmw, tmb, alphas);
    wf_kernel<<<256, 128, 0, stream>>>(W_in, pw, pb, bias, Wf, bf);

    // ext0 = x @ Wf.T + bf  (input projection + W_in0 fused), MFMA
    mfma_gemm<128, true><<<MROWS / 32, 256, 0, stream>>>(x, Wf, bf, buf);
    scan_kernel<<<64, 256, 0, stream>>>(buf, W_rec, alphas, h_carry, 0, 1);

    // ext1 = h0 @ W_in1.T + b1 (f16 A packed in buf rows, in place), MFMA
    mfma_gemm<256, false><<<MROWS / 32, 256, 0, stream>>>(buf, W_in + (size_t)1 * HIDDEN * HIDDEN,
                                                          bias + 1 * HIDDEN, buf);
    scan_kernel<<<64, 256, 0, stream>>>(buf, W_rec + (size_t)1 * HIDDEN * HIDDEN,
                                        alphas + 64, h_carry, 1, 1);

    // ext2 = h1 @ W_in2.T + b2, MFMA
    mfma_gemm<256, false><<<MROWS / 32, 256, 0, stream>>>(buf, W_in + (size_t)2 * HIDDEN * HIDDEN,
                                                          bias + 2 * HIDDEN, buf);
    scan_kernel<<<64, 256, 0, stream>>>(buf, W_rec + (size_t)2 * HIDDEN * HIDDEN,
                                        alphas + 128, h_carry, 2, 0);

    outproj_kernel<<<64, 256, 0, stream>>>(h_carry, ow, ob, out);
}

// Round 15
// 3296.162 us; speedup vs baseline: 2.6267x; 1.0035x over previous
//
#include <hip/hip_runtime.h>
#include <hip/hip_bf16.h>
#include <math.h>
#include <type_traits>

#define HIDDEN 256
#define SEQ 2048
#define BATCH 64
#define INSZ 128
#define OUTSZ 64
#define DTC 0.05f

typedef _Float16 f16x8 __attribute__((ext_vector_type(8)));
typedef float f32x4 __attribute__((ext_vector_type(4)));

// ---------------- K0: complexity net + alphas ----------------
__global__ __launch_bounds__(1024) void prep_kernel(
    const float* __restrict__ x, const float* __restrict__ cw1, const float* __restrict__ cb1,
    const float* __restrict__ cw2, const float* __restrict__ cb2,
    const float* __restrict__ tau_b, const float* __restrict__ tmw, const float* __restrict__ tmb,
    float* __restrict__ alphas)   // [3][64]
{
    __shared__ float p_lds[8][128];
    __shared__ float xm[128];
    __shared__ float t1[64];
    int b = blockIdx.x;
    int tid = threadIdx.x;
    int c = tid & 127, sh = tid >> 7;
    const float* xb = x + (size_t)b * SEQ * INSZ;
    float s = 0.f;
    for (int t = sh * 256; t < (sh + 1) * 256; ++t) s += xb[(size_t)t * INSZ + c];
    p_lds[sh][c] = s;
    __syncthreads();
    if (tid < 128) {
        float m = 0.f;
        #pragma unroll
        for (int i = 0; i < 8; ++i) m += p_lds[i][tid];
        xm[tid] = m / (float)SEQ;
    }
    __syncthreads();
    if (tid < 64) {
        float acc = cb1[tid];
        for (int k = 0; k < 128; ++k) acc += xm[k] * cw1[tid * 128 + k];
        t1[tid] = fmaxf(acc, 0.f);
    }
    __syncthreads();
    if (tid == 0) {
        float acc = cb2[0];
        for (int k = 0; k < 64; ++k) acc += t1[k] * cw2[k];
        float comp = 1.f / (1.f + expf(-acc));
        for (int i = 0; i < 3; ++i) {
            float lg[4], mx = -1e30f;
            for (int j = 0; j < 4; ++j) { lg[j] = comp * tmw[i * 4 + j] + tmb[i * 4 + j]; mx = fmaxf(mx, lg[j]); }
            float den = 0.f;
            for (int j = 0; j < 4; ++j) { lg[j] = expf(lg[j] - mx); den += lg[j]; }
            float mt = 0.f;
            for (int j = 0; j < 4; ++j) mt += tau_b[i * 4 + j] * (lg[j] / den);
            alphas[i * 64 + b] = expf(-DTC / mt);
        }
    }
}

// ---------------- Wf = W_in0 @ pw  (256x128), bf = W_in0 @ pb + bias0 ----------------
__global__ __launch_bounds__(128) void wf_kernel(
    const float* __restrict__ W_in0, const float* __restrict__ pw,
    const float* __restrict__ pb, const float* __restrict__ bias0,
    float* __restrict__ Wf, float* __restrict__ bf)
{
    __shared__ float wrow[256];
    int j = blockIdx.x, k = threadIdx.x;
    for (int m = k; m < 256; m += 128) wrow[m] = W_in0[j * 256 + m];
    __syncthreads();
    float s = 0.f;
    for (int m = 0; m < 256; ++m) s = fmaf(wrow[m], pw[m * 128 + k], s);
    Wf[j * 128 + k] = s;
    if (k == 0) {
        float sb = bias0[j];
        for (int m = 0; m < 256; ++m) sb = fmaf(wrow[m], pb[m], sb);
        bf[j] = sb;
    }
}

__device__ __forceinline__ unsigned pkrtz(float a, float b) {
    return __builtin_bit_cast(unsigned, __builtin_amdgcn_cvt_pkrtz(a, b));
}

// ---------------- MFMA GEMM: C[M][256] = A[M][KD] @ W[256][KD]^T + bias ----------------
// (unchanged from round 14 — verified)
template<int KD, bool SRCF32>
__global__ __launch_bounds__(256, 2) void mfma_gemm(
    const float* __restrict__ Asrc,  // SRCF32: f32 [M][KD]; else f16 packed in 1KB-stride rows
    const float* __restrict__ W,     // [256][KD] f32
    const float* __restrict__ bias,  // [256]
    float* __restrict__ C)           // [M][256] f32
{
    constexpr int KT = KD / 32;
    constexpr int ROWB = KD * 2;     // LDS row bytes (f16)
    __shared__ alignas(16) char alds[32 * ROWB];
    const int tid = threadIdx.x;
    const int wave = tid >> 6, lane = tid & 63;
    const int bl = lane & 15, q = lane >> 4;
    const int m0 = blockIdx.x * 32;

    f16x8 bfrag[4][KT];
    float bv[4];
    #pragma unroll
    for (int nt = 0; nt < 4; ++nt) {
        int n = wave * 64 + nt * 16 + bl;
        const float* wr = W + (size_t)n * KD;
        #pragma unroll
        for (int kt = 0; kt < KT; ++kt) {
            const float4* wp = (const float4*)(wr + kt * 32 + q * 8);
            float4 u0 = wp[0], u1 = wp[1];
            uint4 u = { pkrtz(u0.x, u0.y), pkrtz(u0.z, u0.w),
                        pkrtz(u1.x, u1.y), pkrtz(u1.z, u1.w) };
            bfrag[nt][kt] = __builtin_bit_cast(f16x8, u);
        }
        bv[nt] = bias[n];
    }

    if (SRCF32) {
        #pragma unroll
        for (int it = 0; it < KD / 64; ++it) {
            int idx = tid + it * 256;
            int row = idx >> 4, chunk = idx & 15;
            const float4* sp = (const float4*)(Asrc + (size_t)(m0 + row) * KD + chunk * 8);
            float4 f0 = sp[0], f1 = sp[1];
            uint4 u = { pkrtz(f0.x, f0.y), pkrtz(f0.z, f0.w),
                        pkrtz(f1.x, f1.y), pkrtz(f1.z, f1.w) };
            *(uint4*)(alds + row * ROWB + ((chunk * 16) ^ ((row & 7) << 4))) = u;
        }
    } else {
        #pragma unroll
        for (int it = 0; it < KD / 32; ++it) {
            int idx = tid + it * 256;
            int row = idx >> 5, chunk = idx & 31;
            uint4 u = *(const uint4*)((const char*)Asrc + (size_t)(m0 + row) * 1024 + chunk * 16);
            *(uint4*)(alds + row * ROWB + ((chunk * 16) ^ ((row & 7) << 4))) = u;
        }
    }
    __syncthreads();

    f32x4 acc[2][4];
    #pragma unroll
    for (int mt = 0; mt < 2; ++mt)
        #pragma unroll
        for (int nt = 0; nt < 4; ++nt) acc[mt][nt] = (f32x4){0.f, 0.f, 0.f, 0.f};

    #pragma unroll
    for (int kt = 0; kt < KT; ++kt) {
        int inner = kt * 64 + q * 16;
        f16x8 a0 = __builtin_bit_cast(f16x8,
            *(const uint4*)(alds + (0 * 16 + bl) * ROWB + (inner ^ ((bl & 7) << 4))));
        f16x8 a1 = __builtin_bit_cast(f16x8,
            *(const uint4*)(alds + (1 * 16 + bl) * ROWB + (inner ^ ((bl & 7) << 4))));
        #pragma unroll
        for (int nt = 0; nt < 4; ++nt) {
            acc[0][nt] = __builtin_amdgcn_mfma_f32_16x16x32_f16(a0, bfrag[nt][kt], acc[0][nt], 0, 0, 0);
            acc[1][nt] = __builtin_amdgcn_mfma_f32_16x16x32_f16(a1, bfrag[nt][kt], acc[1][nt], 0, 0, 0);
        }
    }

    #pragma unroll
    for (int mt = 0; mt < 2; ++mt)
        #pragma unroll
        for (int nt = 0; nt < 4; ++nt) {
            int col = wave * 64 + nt * 16 + bl;
            #pragma unroll
            for (int r = 0; r < 4; ++r) {
                int row = m0 + mt * 16 + q * 4 + r;
                C[(size_t)row * 256 + col] = acc[mt][nt][r] + bv[nt];
            }
        }
}

__device__ __forceinline__ float fast_tanh(float x) {
    float ex = __expf(2.f * x);                 // v_exp based
    float r = __builtin_amdgcn_rcpf(ex + 1.f);  // v_rcp_f32
    return 1.f - 2.f * r;                       // ex=inf -> 1, ex=0 -> -1
}

// LDS-only barrier: waits ds ops (lgkmcnt) but leaves global loads/stores in flight.
__device__ __forceinline__ void barrier_lds_only() {
    asm volatile("s_waitcnt lgkmcnt(0)\n\ts_barrier" ::: "memory");
}

// ---------------- MFMA scan v3: 64 WGs x 1 batch, epilogue distributed to ALL lanes ----------------
// Key insight (from r13 counters): with broadcast-B every lane's D columns are REPLICAS,
// so all 64 lanes hold all 16 of the wave's output quadruples. Each thread owns exactly one
// output m = wave*64 + (bl>>2)*16 + q*4 + (bl&3) (bijective over 256 threads) extracted via
// a 15-cndmask in-register select -> 1 tanh/EMA per thread, no elds staging, no masked-lane
// serialization. h in one 512B LDS row (dbuf); per-thread global ext prefetch at column m.
__global__ __launch_bounds__(256, 1) void scan_kernel(
    float* buf,                       // [B][S][256]: in = ext f32, out = h f16 (packed in rows)
    const float* __restrict__ W_rec,  // [256][256]
    const float* __restrict__ alphas, // [64]
    float* __restrict__ h_carry,      // [64][256]
    int layer, int write_all)
{
    __shared__ alignas(16) _Float16 hlds[2][256];   // 2 x 512 B
    const int tid = threadIdx.x;
    const int wave = tid >> 6, lane = tid & 63;
    const int bl = lane & 15, q = lane >> 4;
    const int b = blockIdx.x;
    const int mt_own = bl >> 2, r_own = bl & 3;
    const int m = wave * 64 + mt_own * 16 + q * 4 + r_own;   // this thread's output row

    // ---- A fragments: W rows [wave*64, wave*64+64), 4 m-tiles x 8 k-tiles (AGPR-resident) ----
    f16x8 afrag[4][8];
    #pragma unroll
    for (int mt = 0; mt < 4; ++mt) {
        const float* wr = W_rec + (size_t)(wave * 64 + mt * 16 + bl) * 256;
        #pragma unroll
        for (int kt = 0; kt < 8; ++kt) {
            const float4* wp = (const float4*)(wr + kt * 32 + q * 8);
            float4 wa = wp[0], wb4 = wp[1];
            uint4 u = { pkrtz(wa.x, wa.y), pkrtz(wa.z, wa.w),
                        pkrtz(wb4.x, wb4.y), pkrtz(wb4.z, wb4.w) };
            afrag[mt][kt] = __builtin_bit_cast(f16x8, u);
        }
    }

    const float alpha = alphas[b], onema = 1.f - alpha;
    float* bb = buf + (size_t)b * SEQ * HIDDEN;

    float h_reg = (layer == 0) ? 0.f : h_carry[b * 256 + m];
    hlds[0][m] = (_Float16)h_reg;              // init h buffer 0 (all 256 threads, 2B each)

    float e_cur = bb[m];                       // ext[0][m]
    float e_n1  = bb[(size_t)1 * HIDDEN + m];  // ext[1][m]
    __syncthreads();

    auto step = [&](auto CB, int t) {
        constexpr int CUR = decltype(CB)::value;
        const char* rb = (const char*)&hlds[CUR][0];
        // B fragments: broadcast ds_read_b128 (4 distinct addrs/wave — conflict-free, r13-proven)
        uint4 bq0 = *(const uint4*)(rb + q * 16);
        uint4 bq1 = *(const uint4*)(rb + 64 + q * 16);
        uint4 bq2 = *(const uint4*)(rb + 128 + q * 16);
        uint4 bq3 = *(const uint4*)(rb + 192 + q * 16);
        uint4 bq4 = *(const uint4*)(rb + 256 + q * 16);
        uint4 bq5 = *(const uint4*)(rb + 320 + q * 16);
        uint4 bq6 = *(const uint4*)(rb + 384 + q * 16);
        uint4 bq7 = *(const uint4*)(rb + 448 + q * 16);
        float e_n2 = 0.f;
        if (t + 2 < SEQ) e_n2 = bb[(size_t)(t + 2) * HIDDEN + m];  // 2-ahead prefetch

        f32x4 a0 = {0.f,0.f,0.f,0.f}, a1 = {0.f,0.f,0.f,0.f};
        f32x4 a2 = {0.f,0.f,0.f,0.f}, a3 = {0.f,0.f,0.f,0.f};
        #define MSTEP(BQ, KT) { f16x8 bf = __builtin_bit_cast(f16x8, BQ);                  \
            a0 = __builtin_amdgcn_mfma_f32_16x16x32_f16(afrag[0][KT], bf, a0, 0, 0, 0);    \
            a1 = __builtin_amdgcn_mfma_f32_16x16x32_f16(afrag[1][KT], bf, a1, 0, 0, 0);    \
            a2 = __builtin_amdgcn_mfma_f32_16x16x32_f16(afrag[2][KT], bf, a2, 0, 0, 0);    \
            a3 = __builtin_amdgcn_mfma_f32_16x16x32_f16(afrag[3][KT], bf, a3, 0, 0, 0); }
        MSTEP(bq0, 0) MSTEP(bq1, 1) MSTEP(bq2, 2) MSTEP(bq3, 3)
        MSTEP(bq4, 4) MSTEP(bq5, 5) MSTEP(bq6, 6) MSTEP(bq7, 7)
        #undef MSTEP

        // 16-way in-register select of this thread's output (D cols are replicas)
        f32x4 am = (mt_own == 0) ? a0 : (mt_own == 1) ? a1 : (mt_own == 2) ? a2 : a3;
        float s  = (r_own == 0) ? am[0] : (r_own == 1) ? am[1] : (r_own == 2) ? am[2] : am[3];

        float act = fast_tanh(s + e_cur);
        h_reg = alpha * h_reg + onema * act;
        hlds[CUR ^ 1][m] = (_Float16)h_reg;                  // h for next step
        if (write_all)                                       // h f16 over consumed ext row
            *((_Float16*)(bb + (size_t)t * HIDDEN) + m) = (_Float16)h_reg;
        barrier_lds_only();   // lgkmcnt(0)+s_barrier; global ops stay in flight
        e_cur = e_n1;
        e_n1 = e_n2;
    };

    for (int t = 0; t < SEQ; t += 2) {
        step(std::integral_constant<int, 0>{}, t);
        step(std::integral_constant<int, 1>{}, t + 1);
    }
    h_carry[b * 256 + m] = h_reg;
}

// ---------------- final projection from h_carry ----------------
__global__ __launch_bounds__(256) void outproj_kernel(
    const float* __restrict__ h_carry, const float* __restrict__ ow, const float* __restrict__ ob,
    float* __restrict__ out)
{
    __shared__ float h_l[256];
    __shared__ float p_lds[4][64];
    int b = blockIdx.x;
    int tid = threadIdx.x;
    h_l[tid] = h_carry[b * 256 + tid];
    __syncthreads();
    int o = tid & 63, qq = tid >> 6;
    float s = 0.f;
    const float4* wp = (const float4*)(ow + o * 256 + qq * 64);
    const float4* hp = (const float4*)(h_l + qq * 64);
    #pragma unroll
    for (int m = 0; m < 16; ++m) {
        float4 wv = wp[m]; float4 hv = hp[m];
        s = fmaf(wv.x, hv.x, s); s = fmaf(wv.y, hv.y, s);
        s = fmaf(wv.z, hv.z, s); s = fmaf(wv.w, hv.w, s);
    }
    p_lds[qq][o] = s;
    __syncthreads();
    if (tid < 64)
        out[b * 64 + tid] = p_lds[0][tid] + p_lds[1][tid] + p_lds[2][tid] + p_lds[3][tid] + ob[tid];
}

extern "C" void kernel_launch(void* const* d_in, const int* in_sizes, int n_in,
                              void* d_out, int out_size, void* d_ws, size_t ws_size,
                              hipStream_t stream)
{
    const float* x     = (const float*)d_in[0];
    const float* cw1   = (const float*)d_in[1];
    const float* cb1   = (const float*)d_in[2];
    const float* cw2   = (const float*)d_in[3];
    const float* cb2   = (const float*)d_in[4];
    const float* pw    = (const float*)d_in[5];
    const float* pb    = (const float*)d_in[6];
    const float* W_rec = (const float*)d_in[7];
    const float* W_in  = (const float*)d_in[8];
    const float* bias  = (const float*)d_in[9];
    const float* tau_b = (const float*)d_in[10];
    const float* tmw   = (const float*)d_in[11];
    const float* tmb   = (const float*)d_in[12];
    const float* ow    = (const float*)d_in[13];
    const float* ob    = (const float*)d_in[14];
    float* out = (float*)d_out;

    char* ws = (char*)d_ws;
    float* alphas  = (float*)ws;                       // 192 f
    float* h_carry = (float*)(ws + 4096);              // 64*256 f
    float* bf      = (float*)(ws + 69632);             // 256 f
    float* Wf      = (float*)(ws + 70656);             // 256*128 f
    float* buf     = (float*)(ws + 1048576);           // [64][2048][256] f32 = 134.2MB

    const int MROWS = BATCH * SEQ;      // 131072

    prep_kernel<<<64, 1024, 0, stream>>>(x, cw1, cb1, cw2, cb2, tau_b, tmw, tmb, alphas);
    wf_kernel<<<256, 128, 0, stream>>>(W_in, pw, pb, bias, Wf, bf);

    // ext0 = x @ Wf.T + bf  (input projection + W_in0 fused), MFMA
    mfma_gemm<128, true><<<MROWS / 32, 256, 0, stream>>>(x, Wf, bf, buf);
    scan_kernel<<<64, 256, 0, stream>>>(buf, W_rec, alphas, h_carry, 0, 1);

    // ext1 = h0 @ W_in1.T + b1 (f16 A packed in buf rows, in place), MFMA
    mfma_gemm<256, false><<<MROWS / 32, 256, 0, stream>>>(buf, W_in + (size_t)1 * HIDDEN * HIDDEN,
                                                          bias + 1 * HIDDEN, buf);
    scan_kernel<<<64, 256, 0, stream>>>(buf, W_rec + (size_t)1 * HIDDEN * HIDDEN,
                                        alphas + 64, h_carry, 1, 1);

    // ext2 = h1 @ W_in2.T + b2, MFMA
    mfma_gemm<256, false><<<MROWS / 32, 256, 0, stream>>>(buf, W_in + (size_t)2 * HIDDEN * HIDDEN,
                                                          bias + 2 * HIDDEN, buf);
    scan_kernel<<<64, 256, 0, stream>>>(buf, W_rec + (size_t)2 * HIDDEN * HIDDEN,
                                        alphas + 128, h_carry, 2, 0);

    outproj_kernel<<<64, 256, 0, stream>>>(h_carry, ow, ob, out);
}

// Round 16
// 1721.270 us; speedup vs baseline: 5.0300x; 1.9150x over previous
//
#include <hip/hip_runtime.h>
#include <hip/hip_bf16.h>
#include <math.h>
#include <type_traits>

#define HIDDEN 256
#define SEQ 2048
#define BATCH 64
#define INSZ 128
#define OUTSZ 64
#define DTC 0.05f
#define CCH 8            // pipeline chunks
#define CHS (SEQ / CCH)  // 256 steps per chunk

typedef _Float16 f16x8 __attribute__((ext_vector_type(8)));
typedef float f32x4 __attribute__((ext_vector_type(4)));

// ---------------- K0: complexity net + alphas + zero h_carry slots ----------------
__global__ __launch_bounds__(1024) void prep_kernel(
    const float* __restrict__ x, const float* __restrict__ cw1, const float* __restrict__ cb1,
    const float* __restrict__ cw2, const float* __restrict__ cb2,
    const float* __restrict__ tau_b, const float* __restrict__ tmw, const float* __restrict__ tmb,
    float* __restrict__ alphas, float* __restrict__ h_carry)   // [3][64], [3][64][256]
{
    __shared__ float p_lds[8][128];
    __shared__ float xm[128];
    __shared__ float t1[64];
    int b = blockIdx.x;
    int tid = threadIdx.x;
    // zero all 3 h_carry slots for this batch (speculative init = 0)
    if (tid < 256) {
        h_carry[0 * 16384 + b * 256 + tid] = 0.f;
        h_carry[1 * 16384 + b * 256 + tid] = 0.f;
        h_carry[2 * 16384 + b * 256 + tid] = 0.f;
    }
    int c = tid & 127, sh = tid >> 7;
    const float* xb = x + (size_t)b * SEQ * INSZ;
    float s = 0.f;
    for (int t = sh * 256; t < (sh + 1) * 256; ++t) s += xb[(size_t)t * INSZ + c];
    p_lds[sh][c] = s;
    __syncthreads();
    if (tid < 128) {
        float m = 0.f;
        #pragma unroll
        for (int i = 0; i < 8; ++i) m += p_lds[i][tid];
        xm[tid] = m / (float)SEQ;
    }
    __syncthreads();
    if (tid < 64) {
        float acc = cb1[tid];
        for (int k = 0; k < 128; ++k) acc += xm[k] * cw1[tid * 128 + k];
        t1[tid] = fmaxf(acc, 0.f);
    }
    __syncthreads();
    if (tid == 0) {
        float acc = cb2[0];
        for (int k = 0; k < 64; ++k) acc += t1[k] * cw2[k];
        float comp = 1.f / (1.f + expf(-acc));
        for (int i = 0; i < 3; ++i) {
            float lg[4], mx = -1e30f;
            for (int j = 0; j < 4; ++j) { lg[j] = comp * tmw[i * 4 + j] + tmb[i * 4 + j]; mx = fmaxf(mx, lg[j]); }
            float den = 0.f;
            for (int j = 0; j < 4; ++j) { lg[j] = expf(lg[j] - mx); den += lg[j]; }
            float mt = 0.f;
            for (int j = 0; j < 4; ++j) mt += tau_b[i * 4 + j] * (lg[j] / den);
            alphas[i * 64 + b] = expf(-DTC / mt);
        }
    }
}

// ---------------- Wf = W_in0 @ pw  (256x128), bf = W_in0 @ pb + bias0 ----------------
__global__ __launch_bounds__(128) void wf_kernel(
    const float* __restrict__ W_in0, const float* __restrict__ pw,
    const float* __restrict__ pb, const float* __restrict__ bias0,
    float* __restrict__ Wf, float* __restrict__ bf)
{
    __shared__ float wrow[256];
    int j = blockIdx.x, k = threadIdx.x;
    for (int m = k; m < 256; m += 128) wrow[m] = W_in0[j * 256 + m];
    __syncthreads();
    float s = 0.f;
    for (int m = 0; m < 256; ++m) s = fmaf(wrow[m], pw[m * 128 + k], s);
    Wf[j * 128 + k] = s;
    if (k == 0) {
        float sb = bias0[j];
        for (int m = 0; m < 256; ++m) sb = fmaf(wrow[m], pb[m], sb);
        bf[j] = sb;
    }
}

__device__ __forceinline__ unsigned pkrtz(float a, float b) {
    return __builtin_bit_cast(unsigned, __builtin_amdgcn_cvt_pkrtz(a, b));
}

__device__ __forceinline__ float fast_tanh(float x) {
    float ex = __expf(2.f * x);
    float r = __builtin_amdgcn_rcpf(ex + 1.f);
    return 1.f - 2.f * r;
}

// LDS-only barrier: waits ds ops but leaves global loads/stores in flight.
__device__ __forceinline__ void barrier_lds_only() {
    asm volatile("s_waitcnt lgkmcnt(0)\n\ts_barrier" ::: "memory");
}

// ---------------- standalone MFMA GEMM for ext0 (full seq, r14-verified) ----------------
__global__ __launch_bounds__(256, 2) void gemm0_kernel(
    const float* __restrict__ Asrc,  // x: f32 [M][128]
    const float* __restrict__ W,     // Wf [256][128] f32
    const float* __restrict__ bias,  // bf [256]
    float* __restrict__ C)           // buf [M][256] f32
{
    constexpr int KD = 128, KT = 4, ROWB = 256;
    __shared__ alignas(16) char alds[32 * ROWB];
    const int tid = threadIdx.x;
    const int wave = tid >> 6, lane = tid & 63;
    const int bl = lane & 15, q = lane >> 4;
    const int m0 = blockIdx.x * 32;

    f16x8 bfrag[4][KT];
    float bv[4];
    #pragma unroll
    for (int nt = 0; nt < 4; ++nt) {
        int n = wave * 64 + nt * 16 + bl;
        const float* wr = W + (size_t)n * KD;
        #pragma unroll
        for (int kt = 0; kt < KT; ++kt) {
            const float4* wp = (const float4*)(wr + kt * 32 + q * 8);
            float4 u0 = wp[0], u1 = wp[1];
            uint4 u = { pkrtz(u0.x, u0.y), pkrtz(u0.z, u0.w),
                        pkrtz(u1.x, u1.y), pkrtz(u1.z, u1.w) };
            bfrag[nt][kt] = __builtin_bit_cast(f16x8, u);
        }
        bv[nt] = bias[n];
    }
    #pragma unroll
    for (int it = 0; it < 2; ++it) {
        int idx = tid + it * 256;
        int row = idx >> 4, chunk = idx & 15;
        const float4* sp = (const float4*)(Asrc + (size_t)(m0 + row) * KD + chunk * 8);
        float4 f0 = sp[0], f1 = sp[1];
        uint4 u = { pkrtz(f0.x, f0.y), pkrtz(f0.z, f0.w),
                    pkrtz(f1.x, f1.y), pkrtz(f1.z, f1.w) };
        *(uint4*)(alds + row * ROWB + ((chunk * 16) ^ ((row & 7) << 4))) = u;
    }
    __syncthreads();

    f32x4 acc[2][4];
    #pragma unroll
    for (int mt = 0; mt < 2; ++mt)
        #pragma unroll
        for (int nt = 0; nt < 4; ++nt) acc[mt][nt] = (f32x4){0.f, 0.f, 0.f, 0.f};
    #pragma unroll
    for (int kt = 0; kt < KT; ++kt) {
        int inner = kt * 64 + q * 16;
        f16x8 a0 = __builtin_bit_cast(f16x8,
            *(const uint4*)(alds + (0 * 16 + bl) * ROWB + (inner ^ ((bl & 7) << 4))));
        f16x8 a1 = __builtin_bit_cast(f16x8,
            *(const uint4*)(alds + (1 * 16 + bl) * ROWB + (inner ^ ((bl & 7) << 4))));
        #pragma unroll
        for (int nt = 0; nt < 4; ++nt) {
            acc[0][nt] = __builtin_amdgcn_mfma_f32_16x16x32_f16(a0, bfrag[nt][kt], acc[0][nt], 0, 0, 0);
            acc[1][nt] = __builtin_amdgcn_mfma_f32_16x16x32_f16(a1, bfrag[nt][kt], acc[1][nt], 0, 0, 0);
        }
    }
    #pragma unroll
    for (int mt = 0; mt < 2; ++mt)
        #pragma unroll
        for (int nt = 0; nt < 4; ++nt) {
            int col = wave * 64 + nt * 16 + bl;
            #pragma unroll
            for (int r = 0; r < 4; ++r)
                C[(size_t)(m0 + mt * 16 + q * 4 + r) * 256 + col] = acc[mt][nt][r] + bv[nt];
        }
}

// ---------------- device bodies for the stage megakernel ----------------
// scan chunk (r15 MFMA scan v3 body, chunk-parameterized)
__device__ __forceinline__ void scan_chunk(
    char* smem, float* buf, const float* __restrict__ W_rec,
    const float* __restrict__ alphas, float* __restrict__ h_carry,
    int b, int c, int write_all)
{
    _Float16 (*hlds)[256] = (_Float16 (*)[256])smem;   // [2][256]
    const int tid = threadIdx.x;
    const int wave = tid >> 6, lane = tid & 63;
    const int bl = lane & 15, q = lane >> 4;
    const int mt_own = bl >> 2, r_own = bl & 3;
    const int m = wave * 64 + mt_own * 16 + q * 4 + r_own;

    f16x8 afrag[4][8];
    #pragma unroll
    for (int mt = 0; mt < 4; ++mt) {
        const float* wr = W_rec + (size_t)(wave * 64 + mt * 16 + bl) * 256;
        #pragma unroll
        for (int kt = 0; kt < 8; ++kt) {
            const float4* wp = (const float4*)(wr + kt * 32 + q * 8);
            float4 wa = wp[0], wb4 = wp[1];
            uint4 u = { pkrtz(wa.x, wa.y), pkrtz(wa.z, wa.w),
                        pkrtz(wb4.x, wb4.y), pkrtz(wb4.z, wb4.w) };
            afrag[mt][kt] = __builtin_bit_cast(f16x8, u);
        }
    }

    const float alpha = alphas[b], onema = 1.f - alpha;
    float* bb = buf + (size_t)b * SEQ * HIDDEN;
    const int t0 = c * CHS, tend = t0 + CHS;

    float h_reg = h_carry[b * 256 + m];    // true carry, or speculative 0 at chunk 0
    hlds[0][m] = (_Float16)h_reg;
    float e_cur = bb[(size_t)t0 * HIDDEN + m];
    float e_n1  = bb[(size_t)(t0 + 1) * HIDDEN + m];
    __syncthreads();

    auto step = [&](auto CB, int t) {
        constexpr int CUR = decltype(CB)::value;
        const char* rb = (const char*)&hlds[CUR][0];
        uint4 bq0 = *(const uint4*)(rb + q * 16);
        uint4 bq1 = *(const uint4*)(rb + 64 + q * 16);
        uint4 bq2 = *(const uint4*)(rb + 128 + q * 16);
        uint4 bq3 = *(const uint4*)(rb + 192 + q * 16);
        uint4 bq4 = *(const uint4*)(rb + 256 + q * 16);
        uint4 bq5 = *(const uint4*)(rb + 320 + q * 16);
        uint4 bq6 = *(const uint4*)(rb + 384 + q * 16);
        uint4 bq7 = *(const uint4*)(rb + 448 + q * 16);
        float e_n2 = 0.f;
        if (t + 2 < tend) e_n2 = bb[(size_t)(t + 2) * HIDDEN + m];  // clamp at chunk edge

        f32x4 a0 = {0.f,0.f,0.f,0.f}, a1 = {0.f,0.f,0.f,0.f};
        f32x4 a2 = {0.f,0.f,0.f,0.f}, a3 = {0.f,0.f,0.f,0.f};
        #define MSTEP(BQ, KT) { f16x8 bf = __builtin_bit_cast(f16x8, BQ);                  \
            a0 = __builtin_amdgcn_mfma_f32_16x16x32_f16(afrag[0][KT], bf, a0, 0, 0, 0);    \
            a1 = __builtin_amdgcn_mfma_f32_16x16x32_f16(afrag[1][KT], bf, a1, 0, 0, 0);    \
            a2 = __builtin_amdgcn_mfma_f32_16x16x32_f16(afrag[2][KT], bf, a2, 0, 0, 0);    \
            a3 = __builtin_amdgcn_mfma_f32_16x16x32_f16(afrag[3][KT], bf, a3, 0, 0, 0); }
        MSTEP(bq0, 0) MSTEP(bq1, 1) MSTEP(bq2, 2) MSTEP(bq3, 3)
        MSTEP(bq4, 4) MSTEP(bq5, 5) MSTEP(bq6, 6) MSTEP(bq7, 7)
        #undef MSTEP

        f32x4 am = (mt_own == 0) ? a0 : (mt_own == 1) ? a1 : (mt_own == 2) ? a2 : a3;
        float s  = (r_own == 0) ? am[0] : (r_own == 1) ? am[1] : (r_own == 2) ? am[2] : am[3];

        float act = fast_tanh(s + e_cur);
        h_reg = alpha * h_reg + onema * act;
        hlds[CUR ^ 1][m] = (_Float16)h_reg;
        if (write_all)
            *((_Float16*)(bb + (size_t)t * HIDDEN) + m) = (_Float16)h_reg;
        barrier_lds_only();
        e_cur = e_n1;
        e_n1 = e_n2;
    };

    for (int t = t0; t < tend; t += 2) {
        step(std::integral_constant<int, 0>{}, t);
        step(std::integral_constant<int, 1>{}, t + 1);
    }
    h_carry[b * 256 + m] = h_reg;
}

// ext GEMM chunk: rows = batch g>>3, t-block g&7 within chunk c; KD=256, f16 A in-place
__device__ __forceinline__ void gemm_chunk(
    char* smem, float* buf, const float* __restrict__ W,
    const float* __restrict__ bias, int g, int c)
{
    constexpr int KD = 256, KT = 8, ROWB = 512;
    char* alds = smem;   // 32 * 512 = 16 KB
    const int tid = threadIdx.x;
    const int wave = tid >> 6, lane = tid & 63;
    const int bl = lane & 15, q = lane >> 4;
    const size_t m0 = (size_t)(g >> 3) * SEQ + c * CHS + (g & 7) * 32;

    f16x8 bfrag[4][KT];
    float bv[4];
    #pragma unroll
    for (int nt = 0; nt < 4; ++nt) {
        int n = wave * 64 + nt * 16 + bl;
        const float* wr = W + (size_t)n * KD;
        #pragma unroll
        for (int kt = 0; kt < KT; ++kt) {
            const float4* wp = (const float4*)(wr + kt * 32 + q * 8);
            float4 u0 = wp[0], u1 = wp[1];
            uint4 u = { pkrtz(u0.x, u0.y), pkrtz(u0.z, u0.w),
                        pkrtz(u1.x, u1.y), pkrtz(u1.z, u1.w) };
            bfrag[nt][kt] = __builtin_bit_cast(f16x8, u);
        }
        bv[nt] = bias[n];
    }
    #pragma unroll
    for (int it = 0; it < 8; ++it) {
        int idx = tid + it * 256;
        int row = idx >> 5, chunk = idx & 31;
        uint4 u = *(const uint4*)((const char*)buf + (m0 + row) * 1024 + chunk * 16);
        *(uint4*)(alds + row * ROWB + ((chunk * 16) ^ ((row & 7) << 4))) = u;
    }
    __syncthreads();

    f32x4 acc[2][4];
    #pragma unroll
    for (int mt = 0; mt < 2; ++mt)
        #pragma unroll
        for (int nt = 0; nt < 4; ++nt) acc[mt][nt] = (f32x4){0.f, 0.f, 0.f, 0.f};
    #pragma unroll
    for (int kt = 0; kt < KT; ++kt) {
        int inner = kt * 64 + q * 16;
        f16x8 a0 = __builtin_bit_cast(f16x8,
            *(const uint4*)(alds + (0 * 16 + bl) * ROWB + (inner ^ ((bl & 7) << 4))));
        f16x8 a1 = __builtin_bit_cast(f16x8,
            *(const uint4*)(alds + (1 * 16 + bl) * ROWB + (inner ^ ((bl & 7) << 4))));
        #pragma unroll
        for (int nt = 0; nt < 4; ++nt) {
            acc[0][nt] = __builtin_amdgcn_mfma_f32_16x16x32_f16(a0, bfrag[nt][kt], acc[0][nt], 0, 0, 0);
            acc[1][nt] = __builtin_amdgcn_mfma_f32_16x16x32_f16(a1, bfrag[nt][kt], acc[1][nt], 0, 0, 0);
        }
    }
    #pragma unroll
    for (int mt = 0; mt < 2; ++mt)
        #pragma unroll
        for (int nt = 0; nt < 4; ++nt) {
            int col = wave * 64 + nt * 16 + bl;
            #pragma unroll
            for (int r = 0; r < 4; ++r)
                buf[(m0 + mt * 16 + q * 4 + r) * 256 + col] = acc[mt][nt][r] + bv[nt];
        }
}

// ---------------- stage megakernel: 3 scans + 2 gemms, all independent WGs ----------------
// blocks [0,64): scanL0(stage); [64,128): scanL1(stage-2); [128,192): scanL2(stage-4);
// [192,704): gemm1(stage-1); [704,1216): gemm2(stage-3). Deps ride launch order.
__global__ __launch_bounds__(256, 1) void stage_kernel(
    int stage, float* buf,
    const float* __restrict__ W_rec, const float* __restrict__ W_in,
    const float* __restrict__ bias,  const float* __restrict__ alphas,
    float* __restrict__ h_carry)
{
    __shared__ alignas(16) char smem[16384];
    int blk = blockIdx.x;
    if (blk < 192) {
        int layer = blk >> 6;
        int c = stage - 2 * layer;
        if (c < 0 || c >= CCH) return;
        scan_chunk(smem, buf, W_rec + (size_t)layer * 65536, alphas + layer * 64,
                   h_carry + (size_t)layer * 16384, blk & 63, c, layer < 2);
    } else {
        int g = blk - 192;
        int which = g >> 9;          // 0: ext1 gemm, 1: ext2 gemm
        int gl = g & 511;
        int c = stage - 1 - 2 * which;
        if (c < 0 || c >= CCH) return;
        int lw = which + 1;
        gemm_chunk(smem, buf, W_in + (size_t)lw * 65536, bias + lw * 256, gl, c);
    }
}

// ---------------- final projection from h_carry[2] ----------------
__global__ __launch_bounds__(256) void outproj_kernel(
    const float* __restrict__ h_carry, const float* __restrict__ ow, const float* __restrict__ ob,
    float* __restrict__ out)
{
    __shared__ float h_l[256];
    __shared__ float p_lds[4][64];
    int b = blockIdx.x;
    int tid = threadIdx.x;
    h_l[tid] = h_carry[b * 256 + tid];
    __syncthreads();
    int o = tid & 63, qq = tid >> 6;
    float s = 0.f;
    const float4* wp = (const float4*)(ow + o * 256 + qq * 64);
    const float4* hp = (const float4*)(h_l + qq * 64);
    #pragma unroll
    for (int m = 0; m < 16; ++m) {
        float4 wv = wp[m]; float4 hv = hp[m];
        s = fmaf(wv.x, hv.x, s); s = fmaf(wv.y, hv.y, s);
        s = fmaf(wv.z, hv.z, s); s = fmaf(wv.w, hv.w, s);
    }
    p_lds[qq][o] = s;
    __syncthreads();
    if (tid < 64)
        out[b * 64 + tid] = p_lds[0][tid] + p_lds[1][tid] + p_lds[2][tid] + p_lds[3][tid] + ob[tid];
}

extern "C" void kernel_launch(void* const* d_in, const int* in_sizes, int n_in,
                              void* d_out, int out_size, void* d_ws, size_t ws_size,
                              hipStream_t stream)
{
    const float* x     = (const float*)d_in[0];
    const float* cw1   = (const float*)d_in[1];
    const float* cb1   = (const float*)d_in[2];
    const float* cw2   = (const float*)d_in[3];
    const float* cb2   = (const float*)d_in[4];
    const float* pw    = (const float*)d_in[5];
    const float* pb    = (const float*)d_in[6];
    const float* W_rec = (const float*)d_in[7];
    const float* W_in  = (const float*)d_in[8];
    const float* bias  = (const float*)d_in[9];
    const float* tau_b = (const float*)d_in[10];
    const float* tmw   = (const float*)d_in[11];
    const float* tmb   = (const float*)d_in[12];
    const float* ow    = (const float*)d_in[13];
    const float* ob    = (const float*)d_in[14];
    float* out = (float*)d_out;

    char* ws = (char*)d_ws;
    float* alphas  = (float*)ws;                       // 192 f
    float* h_carry = (float*)(ws + 4096);              // [3][64][256] f = 192KB
    float* bf      = (float*)(ws + 262144);            // 256 f
    float* Wf      = (float*)(ws + 266240);            // 256*128 f
    float* buf     = (float*)(ws + 1048576);           // [64][2048][256] f32 = 134.2MB

    const int MROWS = BATCH * SEQ;      // 131072

    prep_kernel<<<64, 1024, 0, stream>>>(x, cw1, cb1, cw2, cb2, tau_b, tmw, tmb, alphas, h_carry);
    wf_kernel<<<256, 128, 0, stream>>>(W_in, pw, pb, bias, Wf, bf);

    // ext0 = x @ Wf.T + bf (input projection + W_in0 fused), full sequence
    gemm0_kernel<<<MROWS / 32, 256, 0, stream>>>(x, Wf, bf, buf);

    // speculative chunked pipeline: 3 scans + 2 ext-gemms overlapped across launches
    for (int s = 0; s < CCH + 4; ++s)
        stage_kernel<<<1216, 256, 0, stream>>>(s, buf, W_rec, W_in, bias, alphas, h_carry);

    outproj_kernel<<<64, 256, 0, stream>>>(h_carry + 2 * 16384, ow, ob, out);
}

// Round 17
// 1622.615 us; speedup vs baseline: 5.3359x; 1.0608x over previous
//
#include <hip/hip_runtime.h>
#include <hip/hip_bf16.h>
#include <math.h>
#include <type_traits>

#define HIDDEN 256
#define SEQ 2048
#define BATCH 64
#define INSZ 128
#define OUTSZ 64
#define DTC 0.05f
#define CCH 32           // pipeline chunks
#define CHS (SEQ / CCH)  // 64 steps per chunk
#define TBLK (CHS / 32)  // 2 gemm row-blocks per batch-chunk

typedef _Float16 f16x8 __attribute__((ext_vector_type(8)));
typedef float f32x4 __attribute__((ext_vector_type(4)));

// ---------------- K0: complexity net + alphas + zero h_carry slots ----------------
__global__ __launch_bounds__(1024) void prep_kernel(
    const float* __restrict__ x, const float* __restrict__ cw1, const float* __restrict__ cb1,
    const float* __restrict__ cw2, const float* __restrict__ cb2,
    const float* __restrict__ tau_b, const float* __restrict__ tmw, const float* __restrict__ tmb,
    float* __restrict__ alphas, float* __restrict__ h_carry)   // [3][64], [3][64][256]
{
    __shared__ float p_lds[8][128];
    __shared__ float xm[128];
    __shared__ float t1[64];
    int b = blockIdx.x;
    int tid = threadIdx.x;
    // zero all 3 h_carry slots for this batch (speculative init = 0)
    if (tid < 256) {
        h_carry[0 * 16384 + b * 256 + tid] = 0.f;
        h_carry[1 * 16384 + b * 256 + tid] = 0.f;
        h_carry[2 * 16384 + b * 256 + tid] = 0.f;
    }
    int c = tid & 127, sh = tid >> 7;
    const float* xb = x + (size_t)b * SEQ * INSZ;
    float s = 0.f;
    for (int t = sh * 256; t < (sh + 1) * 256; ++t) s += xb[(size_t)t * INSZ + c];
    p_lds[sh][c] = s;
    __syncthreads();
    if (tid < 128) {
        float m = 0.f;
        #pragma unroll
        for (int i = 0; i < 8; ++i) m += p_lds[i][tid];
        xm[tid] = m / (float)SEQ;
    }
    __syncthreads();
    if (tid < 64) {
        float acc = cb1[tid];
        for (int k = 0; k < 128; ++k) acc += xm[k] * cw1[tid * 128 + k];
        t1[tid] = fmaxf(acc, 0.f);
    }
    __syncthreads();
    if (tid == 0) {
        float acc = cb2[0];
        for (int k = 0; k < 64; ++k) acc += t1[k] * cw2[k];
        float comp = 1.f / (1.f + expf(-acc));
        for (int i = 0; i < 3; ++i) {
            float lg[4], mx = -1e30f;
            for (int j = 0; j < 4; ++j) { lg[j] = comp * tmw[i * 4 + j] + tmb[i * 4 + j]; mx = fmaxf(mx, lg[j]); }
            float den = 0.f;
            for (int j = 0; j < 4; ++j) { lg[j] = expf(lg[j] - mx); den += lg[j]; }
            float mt = 0.f;
            for (int j = 0; j < 4; ++j) mt += tau_b[i * 4 + j] * (lg[j] / den);
            alphas[i * 64 + b] = expf(-DTC / mt);
        }
    }
}

// ---------------- Wf = W_in0 @ pw  (256x128), bf = W_in0 @ pb + bias0 ----------------
__global__ __launch_bounds__(128) void wf_kernel(
    const float* __restrict__ W_in0, const float* __restrict__ pw,
    const float* __restrict__ pb, const float* __restrict__ bias0,
    float* __restrict__ Wf, float* __restrict__ bf)
{
    __shared__ float wrow[256];
    int j = blockIdx.x, k = threadIdx.x;
    for (int m = k; m < 256; m += 128) wrow[m] = W_in0[j * 256 + m];
    __syncthreads();
    float s = 0.f;
    for (int m = 0; m < 256; ++m) s = fmaf(wrow[m], pw[m * 128 + k], s);
    Wf[j * 128 + k] = s;
    if (k == 0) {
        float sb = bias0[j];
        for (int m = 0; m < 256; ++m) sb = fmaf(wrow[m], pb[m], sb);
        bf[j] = sb;
    }
}

__device__ __forceinline__ unsigned pkrtz(float a, float b) {
    return __builtin_bit_cast(unsigned, __builtin_amdgcn_cvt_pkrtz(a, b));
}

__device__ __forceinline__ float fast_tanh(float x) {
    float ex = __expf(2.f * x);
    float r = __builtin_amdgcn_rcpf(ex + 1.f);
    return 1.f - 2.f * r;
}

// LDS-only barrier: waits ds ops but leaves global loads/stores in flight.
__device__ __forceinline__ void barrier_lds_only() {
    asm volatile("s_waitcnt lgkmcnt(0)\n\ts_barrier" ::: "memory");
}

// ---------------- standalone MFMA GEMM for ext0 (full seq, r14-verified) ----------------
__global__ __launch_bounds__(256, 2) void gemm0_kernel(
    const float* __restrict__ Asrc,  // x: f32 [M][128]
    const float* __restrict__ W,     // Wf [256][128] f32
    const float* __restrict__ bias,  // bf [256]
    float* __restrict__ C)           // buf [M][256] f32
{
    constexpr int KD = 128, KT = 4, ROWB = 256;
    __shared__ alignas(16) char alds[32 * ROWB];
    const int tid = threadIdx.x;
    const int wave = tid >> 6, lane = tid & 63;
    const int bl = lane & 15, q = lane >> 4;
    const int m0 = blockIdx.x * 32;

    f16x8 bfrag[4][KT];
    float bv[4];
    #pragma unroll
    for (int nt = 0; nt < 4; ++nt) {
        int n = wave * 64 + nt * 16 + bl;
        const float* wr = W + (size_t)n * KD;
        #pragma unroll
        for (int kt = 0; kt < KT; ++kt) {
            const float4* wp = (const float4*)(wr + kt * 32 + q * 8);
            float4 u0 = wp[0], u1 = wp[1];
            uint4 u = { pkrtz(u0.x, u0.y), pkrtz(u0.z, u0.w),
                        pkrtz(u1.x, u1.y), pkrtz(u1.z, u1.w) };
            bfrag[nt][kt] = __builtin_bit_cast(f16x8, u);
        }
        bv[nt] = bias[n];
    }
    #pragma unroll
    for (int it = 0; it < 2; ++it) {
        int idx = tid + it * 256;
        int row = idx >> 4, chunk = idx & 15;
        const float4* sp = (const float4*)(Asrc + (size_t)(m0 + row) * KD + chunk * 8);
        float4 f0 = sp[0], f1 = sp[1];
        uint4 u = { pkrtz(f0.x, f0.y), pkrtz(f0.z, f0.w),
                    pkrtz(f1.x, f1.y), pkrtz(f1.z, f1.w) };
        *(uint4*)(alds + row * ROWB + ((chunk * 16) ^ ((row & 7) << 4))) = u;
    }
    __syncthreads();

    f32x4 acc[2][4];
    #pragma unroll
    for (int mt = 0; mt < 2; ++mt)
        #pragma unroll
        for (int nt = 0; nt < 4; ++nt) acc[mt][nt] = (f32x4){0.f, 0.f, 0.f, 0.f};
    #pragma unroll
    for (int kt = 0; kt < KT; ++kt) {
        int inner = kt * 64 + q * 16;
        f16x8 a0 = __builtin_bit_cast(f16x8,
            *(const uint4*)(alds + (0 * 16 + bl) * ROWB + (inner ^ ((bl & 7) << 4))));
        f16x8 a1 = __builtin_bit_cast(f16x8,
            *(const uint4*)(alds + (1 * 16 + bl) * ROWB + (inner ^ ((bl & 7) << 4))));
        #pragma unroll
        for (int nt = 0; nt < 4; ++nt) {
            acc[0][nt] = __builtin_amdgcn_mfma_f32_16x16x32_f16(a0, bfrag[nt][kt], acc[0][nt], 0, 0, 0);
            acc[1][nt] = __builtin_amdgcn_mfma_f32_16x16x32_f16(a1, bfrag[nt][kt], acc[1][nt], 0, 0, 0);
        }
    }
    #pragma unroll
    for (int mt = 0; mt < 2; ++mt)
        #pragma unroll
        for (int nt = 0; nt < 4; ++nt) {
            int col = wave * 64 + nt * 16 + bl;
            #pragma unroll
            for (int r = 0; r < 4; ++r)
                C[(size_t)(m0 + mt * 16 + q * 4 + r) * 256 + col] = acc[mt][nt][r] + bv[nt];
        }
}

// ---------------- device bodies for the stage megakernel ----------------
// scan chunk (r15 MFMA scan v3 body, chunk-parameterized)
__device__ __forceinline__ void scan_chunk(
    char* smem, float* buf, const float* __restrict__ W_rec,
    const float* __restrict__ alphas, float* __restrict__ h_carry,
    int b, int c, int write_all)
{
    _Float16 (*hlds)[256] = (_Float16 (*)[256])smem;   // [2][256]
    const int tid = threadIdx.x;
    const int wave = tid >> 6, lane = tid & 63;
    const int bl = lane & 15, q = lane >> 4;
    const int mt_own = bl >> 2, r_own = bl & 3;
    const int m = wave * 64 + mt_own * 16 + q * 4 + r_own;

    f16x8 afrag[4][8];
    #pragma unroll
    for (int mt = 0; mt < 4; ++mt) {
        const float* wr = W_rec + (size_t)(wave * 64 + mt * 16 + bl) * 256;
        #pragma unroll
        for (int kt = 0; kt < 8; ++kt) {
            const float4* wp = (const float4*)(wr + kt * 32 + q * 8);
            float4 wa = wp[0], wb4 = wp[1];
            uint4 u = { pkrtz(wa.x, wa.y), pkrtz(wa.z, wa.w),
                        pkrtz(wb4.x, wb4.y), pkrtz(wb4.z, wb4.w) };
            afrag[mt][kt] = __builtin_bit_cast(f16x8, u);
        }
    }

    const float alpha = alphas[b], onema = 1.f - alpha;
    float* bb = buf + (size_t)b * SEQ * HIDDEN;
    const int t0 = c * CHS, tend = t0 + CHS;

    float h_reg = h_carry[b * 256 + m];    // true carry, or speculative 0 at chunk 0
    hlds[0][m] = (_Float16)h_reg;
    float e_cur = bb[(size_t)t0 * HIDDEN + m];
    float e_n1  = bb[(size_t)(t0 + 1) * HIDDEN + m];
    __syncthreads();

    auto step = [&](auto CB, int t) {
        constexpr int CUR = decltype(CB)::value;
        const char* rb = (const char*)&hlds[CUR][0];
        uint4 bq0 = *(const uint4*)(rb + q * 16);
        uint4 bq1 = *(const uint4*)(rb + 64 + q * 16);
        uint4 bq2 = *(const uint4*)(rb + 128 + q * 16);
        uint4 bq3 = *(const uint4*)(rb + 192 + q * 16);
        uint4 bq4 = *(const uint4*)(rb + 256 + q * 16);
        uint4 bq5 = *(const uint4*)(rb + 320 + q * 16);
        uint4 bq6 = *(const uint4*)(rb + 384 + q * 16);
        uint4 bq7 = *(const uint4*)(rb + 448 + q * 16);
        float e_n2 = 0.f;
        if (t + 2 < tend) e_n2 = bb[(size_t)(t + 2) * HIDDEN + m];  // clamp at chunk edge

        f32x4 a0 = {0.f,0.f,0.f,0.f}, a1 = {0.f,0.f,0.f,0.f};
        f32x4 a2 = {0.f,0.f,0.f,0.f}, a3 = {0.f,0.f,0.f,0.f};
        #define MSTEP(BQ, KT) { f16x8 bf = __builtin_bit_cast(f16x8, BQ);                  \
            a0 = __builtin_amdgcn_mfma_f32_16x16x32_f16(afrag[0][KT], bf, a0, 0, 0, 0);    \
            a1 = __builtin_amdgcn_mfma_f32_16x16x32_f16(afrag[1][KT], bf, a1, 0, 0, 0);    \
            a2 = __builtin_amdgcn_mfma_f32_16x16x32_f16(afrag[2][KT], bf, a2, 0, 0, 0);    \
            a3 = __builtin_amdgcn_mfma_f32_16x16x32_f16(afrag[3][KT], bf, a3, 0, 0, 0); }
        MSTEP(bq0, 0) MSTEP(bq1, 1) MSTEP(bq2, 2) MSTEP(bq3, 3)
        MSTEP(bq4, 4) MSTEP(bq5, 5) MSTEP(bq6, 6) MSTEP(bq7, 7)
        #undef MSTEP

        f32x4 am = (mt_own == 0) ? a0 : (mt_own == 1) ? a1 : (mt_own == 2) ? a2 : a3;
        float s  = (r_own == 0) ? am[0] : (r_own == 1) ? am[1] : (r_own == 2) ? am[2] : am[3];

        float act = fast_tanh(s + e_cur);
        h_reg = alpha * h_reg + onema * act;
        hlds[CUR ^ 1][m] = (_Float16)h_reg;
        if (write_all)
            *((_Float16*)(bb + (size_t)t * HIDDEN) + m) = (_Float16)h_reg;
        barrier_lds_only();
        e_cur = e_n1;
        e_n1 = e_n2;
    };

    for (int t = t0; t < tend; t += 2) {
        step(std::integral_constant<int, 0>{}, t);
        step(std::integral_constant<int, 1>{}, t + 1);
    }
    h_carry[b * 256 + m] = h_reg;
}

// ext GEMM chunk: rows = batch g/TBLK, t-block g%TBLK within chunk c; KD=256, f16 A in-place
__device__ __forceinline__ void gemm_chunk(
    char* smem, float* buf, const float* __restrict__ W,
    const float* __restrict__ bias, int g, int c)
{
    constexpr int KD = 256, KT = 8, ROWB = 512;
    char* alds = smem;   // 32 * 512 = 16 KB
    const int tid = threadIdx.x;
    const int wave = tid >> 6, lane = tid & 63;
    const int bl = lane & 15, q = lane >> 4;
    const size_t m0 = (size_t)(g / TBLK) * SEQ + c * CHS + (g % TBLK) * 32;

    f16x8 bfrag[4][KT];
    float bv[4];
    #pragma unroll
    for (int nt = 0; nt < 4; ++nt) {
        int n = wave * 64 + nt * 16 + bl;
        const float* wr = W + (size_t)n * KD;
        #pragma unroll
        for (int kt = 0; kt < KT; ++kt) {
            const float4* wp = (const float4*)(wr + kt * 32 + q * 8);
            float4 u0 = wp[0], u1 = wp[1];
            uint4 u = { pkrtz(u0.x, u0.y), pkrtz(u0.z, u0.w),
                        pkrtz(u1.x, u1.y), pkrtz(u1.z, u1.w) };
            bfrag[nt][kt] = __builtin_bit_cast(f16x8, u);
        }
        bv[nt] = bias[n];
    }
    #pragma unroll
    for (int it = 0; it < 8; ++it) {
        int idx = tid + it * 256;
        int row = idx >> 5, chunk = idx & 31;
        uint4 u = *(const uint4*)((const char*)buf + (m0 + row) * 1024 + chunk * 16);
        *(uint4*)(alds + row * ROWB + ((chunk * 16) ^ ((row & 7) << 4))) = u;
    }
    __syncthreads();

    f32x4 acc[2][4];
    #pragma unroll
    for (int mt = 0; mt < 2; ++mt)
        #pragma unroll
        for (int nt = 0; nt < 4; ++nt) acc[mt][nt] = (f32x4){0.f, 0.f, 0.f, 0.f};
    #pragma unroll
    for (int kt = 0; kt < KT; ++kt) {
        int inner = kt * 64 + q * 16;
        f16x8 a0 = __builtin_bit_cast(f16x8,
            *(const uint4*)(alds + (0 * 16 + bl) * ROWB + (inner ^ ((bl & 7) << 4))));
        f16x8 a1 = __builtin_bit_cast(f16x8,
            *(const uint4*)(alds + (1 * 16 + bl) * ROWB + (inner ^ ((bl & 7) << 4))));
        #pragma unroll
        for (int nt = 0; nt < 4; ++nt) {
            acc[0][nt] = __builtin_amdgcn_mfma_f32_16x16x32_f16(a0, bfrag[nt][kt], acc[0][nt], 0, 0, 0);
            acc[1][nt] = __builtin_amdgcn_mfma_f32_16x16x32_f16(a1, bfrag[nt][kt], acc[1][nt], 0, 0, 0);
        }
    }
    #pragma unroll
    for (int mt = 0; mt < 2; ++mt)
        #pragma unroll
        for (int nt = 0; nt < 4; ++nt) {
            int col = wave * 64 + nt * 16 + bl;
            #pragma unroll
            for (int r = 0; r < 4; ++r)
                buf[(m0 + mt * 16 + q * 4 + r) * 256 + col] = acc[mt][nt][r] + bv[nt];
        }
}

// ---------------- stage megakernel: 3 scans + 2 gemms, all independent WGs ----------------
// blocks [0,64): scanL0(stage); [64,128): scanL1(stage-2); [128,192): scanL2(stage-4);
// [192,192+64*TBLK): gemm1(stage-1); next 64*TBLK: gemm2(stage-3). Deps ride launch order.
__global__ __launch_bounds__(256, 1) void stage_kernel(
    int stage, float* buf,
    const float* __restrict__ W_rec, const float* __restrict__ W_in,
    const float* __restrict__ bias,  const float* __restrict__ alphas,
    float* __restrict__ h_carry)
{
    __shared__ alignas(16) char smem[16384];
    int blk = blockIdx.x;
    if (blk < 192) {
        int layer = blk >> 6;
        int c = stage - 2 * layer;
        if (c < 0 || c >= CCH) return;
        scan_chunk(smem, buf, W_rec + (size_t)layer * 65536, alphas + layer * 64,
                   h_carry + (size_t)layer * 16384, blk & 63, c, layer < 2);
    } else {
        int g = blk - 192;
        int which = g / (64 * TBLK);   // 0: ext1 gemm, 1: ext2 gemm
        int gl = g % (64 * TBLK);
        int c = stage - 1 - 2 * which;
        if (c < 0 || c >= CCH) return;
        int lw = which + 1;
        gemm_chunk(smem, buf, W_in + (size_t)lw * 65536, bias + lw * 256, gl, c);
    }
}

// ---------------- final projection from h_carry[2] ----------------
__global__ __launch_bounds__(256) void outproj_kernel(
    const float* __restrict__ h_carry, const float* __restrict__ ow, const float* __restrict__ ob,
    float* __restrict__ out)
{
    __shared__ float h_l[256];
    __shared__ float p_lds[4][64];
    int b = blockIdx.x;
    int tid = threadIdx.x;
    h_l[tid] = h_carry[b * 256 + tid];
    __syncthreads();
    int o = tid & 63, qq = tid >> 6;
    float s = 0.f;
    const float4* wp = (const float4*)(ow + o * 256 + qq * 64);
    const float4* hp = (const float4*)(h_l + qq * 64);
    #pragma unroll
    for (int m = 0; m < 16; ++m) {
        float4 wv = wp[m]; float4 hv = hp[m];
        s = fmaf(wv.x, hv.x, s); s = fmaf(wv.y, hv.y, s);
        s = fmaf(wv.z, hv.z, s); s = fmaf(wv.w, hv.w, s);
    }
    p_lds[qq][o] = s;
    __syncthreads();
    if (tid < 64)
        out[b * 64 + tid] = p_lds[0][tid] + p_lds[1][tid] + p_lds[2][tid] + p_lds[3][tid] + ob[tid];
}

extern "C" void kernel_launch(void* const* d_in, const int* in_sizes, int n_in,
                              void* d_out, int out_size, void* d_ws, size_t ws_size,
                              hipStream_t stream)
{
    const float* x     = (const float*)d_in[0];
    const float* cw1   = (const float*)d_in[1];
    const float* cb1   = (const float*)d_in[2];
    const float* cw2   = (const float*)d_in[3];
    const float* cb2   = (const float*)d_in[4];
    const float* pw    = (const float*)d_in[5];
    const float* pb    = (const float*)d_in[6];
    const float* W_rec = (const float*)d_in[7];
    const float* W_in  = (const float*)d_in[8];
    const float* bias  = (const float*)d_in[9];
    const float* tau_b = (const float*)d_in[10];
    const float* tmw   = (const float*)d_in[11];
    const float* tmb   = (const float*)d_in[12];
    const float* ow    = (const float*)d_in[13];
    const float* ob    = (const float*)d_in[14];
    float* out = (float*)d_out;

    char* ws = (char*)d_ws;
    float* alphas  = (float*)ws;                       // 192 f
    float* h_carry = (float*)(ws + 4096);              // [3][64][256] f = 192KB
    float* bf      = (float*)(ws + 262144);            // 256 f
    float* Wf      = (float*)(ws + 266240);            // 256*128 f
    float* buf     = (float*)(ws + 1048576);           // [64][2048][256] f32 = 134.2MB

    const int MROWS = BATCH * SEQ;      // 131072
    const int NGBLK = 192 + 2 * 64 * TBLK;   // 448 blocks per stage

    prep_kernel<<<64, 1024, 0, stream>>>(x, cw1, cb1, cw2, cb2, tau_b, tmw, tmb, alphas, h_carry);
    wf_kernel<<<256, 128, 0, stream>>>(W_in, pw, pb, bias, Wf, bf);

    // ext0 = x @ Wf.T + bf (input projection + W_in0 fused), full sequence
    gemm0_kernel<<<MROWS / 32, 256, 0, stream>>>(x, Wf, bf, buf);

    // speculative chunked pipeline: 3 scans + 2 ext-gemms overlapped across launches
    for (int s = 0; s < CCH + 4; ++s)
        stage_kernel<<<NGBLK, 256, 0, stream>>>(s, buf, W_rec, W_in, bias, alphas, h_carry);

    outproj_kernel<<<64, 256, 0, stream>>>(h_carry + 2 * 16384, ow, ob, out);
}